// Round 7
// baseline (361.454 us; speedup 1.0000x reference)
//
#include <hip/hip_runtime.h>
#include <hip/hip_bf16.h>

typedef __hip_bfloat16 bf16;
typedef __attribute__((ext_vector_type(8))) short short8;
typedef __attribute__((ext_vector_type(4))) float floatx4;
typedef __bf16 bf16x8 __attribute__((ext_vector_type(8)));

// ---------------- workspace layout ----------------
// float offsets
#define OFF_A1 0
#define OFF_C1 64
#define OFF_A2 128
#define OFF_C2 160
#define OFF_A3 192
#define OFF_C3 224
#define OFF_LP 256
#define OFF_P1S 512
#define OFF_P1Q 66048            // P1S + 1024*64
#define OFF_P2S 131584           // P1Q + 1024*64
#define OFF_P2Q 205312           // P2S + 2304*32

// byte offsets
#define FW2_BYTE 2295808u
#define FW3_BYTE 2332672u        // + 2304*8*2
#define FW4_BYTE 2351104u        // + 1152*8*2 ; fw4: [r3][d10][L64][8] = 30720 B
#define X2_BYTE  33546240u       // x2 (36,27,1024,32) bf16
#define X3_BYTE  97247232u       // x3 (36,55,1024,32) bf16
#define O4_BYTE  227008512u      // o4 (1024,36,105) f32  (also holds BN3 partials pre-dc4)

// BN3 partials live in the o4 region (consumed by fin3 BEFORE k_dc4 writes o4)
#define P3S_ABS 56752128         // O4_BYTE/4
#define P3Q_ABS 56973312         // + 6912*32

// ---------------- d_out layout (float offsets) ----------------
#define OUT0 0
#define OUT1 153600
#define OUT2 155340
#define OUT3 2827980
#define OUT4 2858700
#define OUT5 3749580
#define OUT6 3780300
#define OUT7 3933900
#define OUT8 6606540
#define OUT9 6637260
#define OUT10 7528140

__device__ __forceinline__ bf16 f2b(float v){ return __float2bfloat16(v); }
__device__ __forceinline__ unsigned short f2bu(float v){ bf16 h = __float2bfloat16(v); return *(unsigned short*)&h; }

__device__ __forceinline__ floatx4 mfma16(short8 a, short8 b, floatx4 c){
  return __builtin_amdgcn_mfma_f32_16x16x32_bf16(__builtin_bit_cast(bf16x8, a),
                                                 __builtin_bit_cast(bf16x8, b), c, 0, 0, 0);
}

__device__ __forceinline__ unsigned int nrm2(unsigned int u, float a0, float c0, float a1, float c1){
  float x0 = __uint_as_float(u << 16);
  float x1 = __uint_as_float(u & 0xffff0000u);
  float y0 = fmaxf(fmaf(a0, x0, c0), 0.f);
  float y1 = fmaxf(fmaf(a1, x1, c1), 0.f);
  return (unsigned int)f2bu(y0) | ((unsigned int)f2bu(y1) << 16);
}

__device__ __forceinline__ void gload_lds16(const unsigned short* g, unsigned short* lds){
  __builtin_amdgcn_global_load_lds((const __attribute__((address_space(1))) unsigned int*)g,
                                   (__attribute__((address_space(3))) unsigned int*)lds, 16, 0, 0);
}

// ============ weight fragment prep ============
__global__ __launch_bounds__(256) void k_prep(const float* __restrict__ W2, const float* __restrict__ W3,
                                              const float* __restrict__ W4,
                                              unsigned short* __restrict__ fw2, unsigned short* __restrict__ fw3,
                                              unsigned short* __restrict__ fw4){
  const int t = blockIdx.x*256 + threadIdx.x;
  if (t < 2304){   // fw2: [tap9][mt2][kc2][L64][8]
    const int L = t & 63, kc = (t>>6)&1, mt = (t>>7)&1, tap = t>>8;
    const int co = mt*16 + (L&15), ci0 = kc*32 + ((L>>4)&3)*8;
    #pragma unroll
    for (int j = 0; j < 8; ++j)
      fw2[(size_t)t*8 + j] = f2bu(W2[((size_t)tap*64 + ci0 + j)*32 + co]);
  }
  if (t < 1152){   // fw3: [tap9][mt2][L64][8]
    const int L = t & 63, mt = (t>>6)&1, tap = t>>7;
    const int co = mt*16 + (L&15), ci0 = ((L>>4)&3)*8;
    #pragma unroll
    for (int j = 0; j < 8; ++j)
      fw3[(size_t)t*8 + j] = f2bu(W3[((size_t)tap*32 + ci0 + j)*32 + co]);
  }
  if (t < 1920){   // fw4: banded layer-4 A-frags [r3][d10][L64][8]; A[m][ci] = W4[r][kw=2d-m][ci]
    const int L = t & 63, d = (t>>6) % 10, r = t / 640;
    const int m = L & 15, ci0 = ((L>>4)&3)*8;
    const int kw = 2*d - m;
    #pragma unroll
    for (int j = 0; j < 8; ++j)
      fw4[(size_t)t*8 + j] = (kw >= 0 && kw < 5) ? f2bu(W4[(r*5 + kw)*32 + ci0 + j])
                                                 : (unsigned short)0;
  }
}

// ============ layer-1 stats only ============
__global__ __launch_bounds__(256) void k_dc1(const float* __restrict__ Z, const float* __restrict__ W1,
                                             float* __restrict__ ws){
  const int b = blockIdx.x, t = threadIdx.x;
  __shared__ float zs[32];
  __shared__ float w1s[3*7*64];
  __shared__ float red[256];
  if (t < 32) zs[t] = Z[b*32 + t];
  for (int i = t; i < 1344; i += 256) w1s[i] = W1[i];
  __syncthreads();
  float lsum = 0.f, lsq = 0.f;
  for (int idx = t; idx < 15232; idx += 256){
    int co = idx & 63;
    int wo = (idx >> 6) % 7;
    int ho = idx / 448;
    int kw = 6 - wo;
    float y = 0.f;
    #pragma unroll
    for (int kh = 0; kh < 3; ++kh){
      int hi = ho + kh - 2;
      if (hi >= 0 && hi < 32) y += zs[hi] * w1s[(kh*7 + kw)*64 + co];
    }
    lsum += y; lsq += y*y;
  }
  red[t] = lsum; __syncthreads();
  if (t < 64) ws[OFF_P1S + b*64 + t] = red[t] + red[t+64] + red[t+128] + red[t+192];
  __syncthreads();
  red[t] = lsq; __syncthreads();
  if (t < 64) ws[OFF_P1Q + b*64 + t] = red[t] + red[t+64] + red[t+128] + red[t+192];
}

// ============ BN finalize: partials laid out [part][nch] ============
__global__ __launch_bounds__(256) void k_fin(float* __restrict__ ws, const float* __restrict__ g,
                                             const float* __restrict__ bb, int ps, int pq, int npart,
                                             int nch, float inv_n, int ao, int co, int zlp){
  const int c = blockIdx.x, t = threadIdx.x;
  __shared__ float r1[256], r2[256];
  float s = 0.f, q = 0.f;
  for (int i = t; i < npart; i += 256){ s += ws[ps + i*nch + c]; q += ws[pq + i*nch + c]; }
  r1[t] = s; r2[t] = q; __syncthreads();
  for (int off = 128; off > 0; off >>= 1){
    if (t < off){ r1[t] += r1[t+off]; r2[t] += r2[t+off]; }
    __syncthreads();
  }
  if (t == 0){
    float m  = r1[0] * inv_n;
    float v  = r2[0] * inv_n - m*m;
    float is = rsqrtf(v + 1e-5f);
    float a  = g[c] * is;
    ws[ao + c] = a;
    ws[co + c] = bb[c] - a*m;
  }
  if (zlp && c == 0 && t == 0) ws[OFF_LP] = 0.f;
}

// ============ deconv2 (MFMA): Z -> (recompute act1) -> x2 (36,27,1024,32) ============
__global__ __launch_bounds__(256) void k2(const float* __restrict__ Z, const float* __restrict__ W1,
                                          const unsigned short* __restrict__ fw2,
                                          unsigned short* __restrict__ x2, float* __restrict__ ws){
  const int t = threadIdx.x;
  const int b0 = blockIdx.x*16, ho = blockIdx.y;
  __shared__ unsigned short sa[21*1024];
  __shared__ float zs[16][32];
  __shared__ float w1s[1344];
  __shared__ float sa1[64], sc1[64];
  __shared__ float sred[2][4][32];
  if (t < 64){ sa1[t] = ws[OFF_A1+t]; sc1[t] = ws[OFF_C1+t]; }
  for (int i = t; i < 512; i += 256) zs[i>>5][i&31] = Z[(b0 + (i>>5))*32 + (i&31)];
  for (int i = t; i < 1344; i += 256) w1s[i] = W1[i];
  __syncthreads();
  for (int c = t; c < 21*128; c += 256){
    const int p = c >> 7, g = c & 127;
    const int r = p/7, wi = p - r*7;
    const int hi = ho - 2 + r;
    const int b = g >> 3, kc = (g >> 2) & 1, j = g & 3;
    const int ci0 = kc*32 + j*8;
    unsigned int pk[4] = {0,0,0,0};
    if (hi >= 0 && hi < 34){
      const float* wp = &w1s[(6 - wi)*64 + ci0];
      #pragma unroll
      for (int e = 0; e < 8; e += 2){
        float y0 = 0.f, y1 = 0.f;
        #pragma unroll
        for (int kh = 0; kh < 3; ++kh){
          const int q = hi + kh - 2;
          if (q >= 0 && q < 32){
            float zv = zs[b][q];
            y0 += zv * wp[kh*448 + e];
            y1 += zv * wp[kh*448 + e + 1];
          }
        }
        float u0 = fmaxf(fmaf(sa1[ci0+e],   y0, sc1[ci0+e]),   0.f);
        float u1 = fmaxf(fmaf(sa1[ci0+e+1], y1, sc1[ci0+e+1]), 0.f);
        pk[e>>1] = (unsigned int)f2bu(u0) | ((unsigned int)f2bu(u1) << 16);
      }
    }
    *(uint4*)(sa + (size_t)p*1024 + kc*512 + (j*16 + b)*8) = *(uint4*)pk;
  }
  __syncthreads();
  const int w = t>>6, L = t&63;
  floatx4 acc[8][2];
  #pragma unroll
  for (int i = 0; i < 8; ++i){ acc[i][0] = (floatx4)0.f; acc[i][1] = (floatx4)0.f; }
  const int wiA = 2*w, wiB = (w < 3) ? 2*w + 1 : 2*w;
  for (int r = 0; r < 3; ++r){
    short8 af[3][2][2];
    #pragma unroll
    for (int kw = 0; kw < 3; ++kw)
      #pragma unroll
      for (int mt = 0; mt < 2; ++mt)
        #pragma unroll
        for (int kc = 0; kc < 2; ++kc)
          af[kw][mt][kc] = *(const short8*)(fw2 + ((((size_t)(r*3+kw)*2 + mt)*2 + kc)*64 + L)*8);
    const short8* pA = (const short8*)(sa + (size_t)(r*7 + wiA)*1024);
    const short8* pB = (const short8*)(sa + (size_t)(r*7 + wiB)*1024);
    short8 fa0 = pA[L], fa1 = pA[64+L];
    short8 fb0 = pB[L], fb1 = pB[64+L];
    #pragma unroll
    for (int idx = 0; idx < 8; ++idx){
      if (idx == 3 || idx == 7) continue;
      const int kw = (2 - idx) & 3;
      const int half = idx >> 2;
      if (half && w == 3) continue;
      short8 f0 = half ? fb0 : fa0;
      short8 f1 = half ? fb1 : fa1;
      #pragma unroll
      for (int mt = 0; mt < 2; ++mt){
        acc[idx][mt] = mfma16(af[kw][mt][0], f0, acc[idx][mt]);
        acc[idx][mt] = mfma16(af[kw][mt][1], f1, acc[idx][mt]);
      }
    }
  }
  const int bL = L & 15, jj = (L>>4)&3;
  float ss[2][4] = {{0,0,0,0},{0,0,0,0}}, sq[2][4] = {{0,0,0,0},{0,0,0,0}};
  #pragma unroll
  for (int idx = 0; idx < 8; ++idx){
    if (8*w + idx >= 27) continue;
    #pragma unroll
    for (int mt = 0; mt < 2; ++mt){
      floatx4 a = acc[idx][mt];
      ss[mt][0] += a.x; ss[mt][1] += a.y; ss[mt][2] += a.z; ss[mt][3] += a.w;
      sq[mt][0] += a.x*a.x; sq[mt][1] += a.y*a.y; sq[mt][2] += a.z*a.z; sq[mt][3] += a.w*a.w;
    }
  }
  #pragma unroll
  for (int mt = 0; mt < 2; ++mt)
    #pragma unroll
    for (int r2 = 0; r2 < 4; ++r2){
      float v1 = ss[mt][r2], v2 = sq[mt][r2];
      for (int d = 1; d < 16; d <<= 1){ v1 += __shfl_xor(v1, d, 64); v2 += __shfl_xor(v2, d, 64); }
      if (bL == 0){
        int cch = mt*16 + jj*4 + r2;
        sred[0][w][cch] = v1;
        sred[1][w][cch] = v2;
      }
    }
  __syncthreads();
  if (t < 64){
    const int cch = t & 31, j2 = t >> 5;
    float tot = sred[j2][0][cch] + sred[j2][1][cch] + sred[j2][2][cch] + sred[j2][3][cch];
    const int bid = blockIdx.y*64 + blockIdx.x;
    ws[(j2 ? OFF_P2Q : OFF_P2S) + bid*32 + cch] = tot;
  }
  unsigned short* st = sa + w*4608;
  #pragma unroll
  for (int idx = 0; idx < 8; ++idx){
    if (8*w + idx >= 27) continue;
    #pragma unroll
    for (int mt = 0; mt < 2; ++mt){
      floatx4 a = acc[idx][mt];
      uint2 pk;
      pk.x = (unsigned int)f2bu(a.x) | ((unsigned int)f2bu(a.y) << 16);
      pk.y = (unsigned int)f2bu(a.z) | ((unsigned int)f2bu(a.w) << 16);
      *(uint2*)(st + idx*576 + bL*36 + mt*16 + jj*4) = pk;
    }
  }
  const int sb = L >> 2, q2 = L & 3;
  #pragma unroll
  for (int idx = 0; idx < 8; ++idx){
    const int wo = 8*w + idx;
    if (wo >= 27) continue;
    uint4 v = *(const uint4*)(st + idx*576 + sb*36 + q2*8);
    *(uint4*)(x2 + ((size_t)(ho*27+wo)*1024 + b0 + sb)*32 + q2*8) = v;
  }
}

// ============ deconv3 (MFMA, DMA-staged): x2 -> x3 (36,55,1024,32) ============
// 3-way wo split (18/18/19), even s0 per wave; staging via global_load_lds in frag order;
// BN+ReLU applied as in-LDS RMW pass.
__global__ __launch_bounds__(256) void k3(const unsigned short* __restrict__ x2, const unsigned short* __restrict__ fw3,
                                          unsigned short* __restrict__ x3, float* __restrict__ ws){
  const int t = threadIdx.x;
  const int b0 = blockIdx.x*16, ho = blockIdx.y, z = blockIdx.z;
  const int wib = (z == 0) ? 0 : ((z == 1) ? 8 : 17);
  __shared__ unsigned short sa[33*512];      // 3r x 11wi pixels, frag order; reused as store buffer
  __shared__ float sa2[32], sc2[32];
  __shared__ float sred[2][4][32];
  if (t < 32){ sa2[t] = ws[OFF_A2+t]; sc2[t] = ws[OFF_C2+t]; }
  const int w = t>>6, L = t&63;
  const int bL = L & 15, jL = (L>>4)&3, ci0 = jL*8;
  // async DMA staging: lane L fetches chunk (b=bL, ci-group=jL) -> LDS offset L*16
  for (int p = w; p < 33; p += 4){
    const int r = p/11, wl = p - r*11;
    const int hi = ho - 1 + r, wi = wib + wl;
    unsigned short* dst = sa + p*512;
    if (hi >= 0 && hi < 36 && wi < 27){
      const unsigned short* src = x2 + ((size_t)(hi*27 + wi)*1024 + b0 + bL)*32 + ci0;
      gload_lds16(src, dst);
    } else {
      *(uint4*)(dst + L*8) = make_uint4(0,0,0,0);
    }
  }
  __syncthreads();
  // in-LDS BN+ReLU (skip invalid pixels: they stay zero)
  {
    float an[8], cn[8];
    #pragma unroll
    for (int e = 0; e < 8; ++e){ an[e] = sa2[ci0+e]; cn[e] = sc2[ci0+e]; }
    for (int i = t; i < 2112; i += 256){
      const int p = i >> 6;                    // wave-uniform
      const int r = p/11, wl = p - r*11;
      const int hi = ho - 1 + r, wi = wib + wl;
      if (hi >= 0 && hi < 36 && wi < 27){
        uint4 v = *(uint4*)(sa + (size_t)i*8);
        v.x = nrm2(v.x, an[0], cn[0], an[1], cn[1]);
        v.y = nrm2(v.y, an[2], cn[2], an[3], cn[3]);
        v.z = nrm2(v.z, an[4], cn[4], an[5], cn[5]);
        v.w = nrm2(v.w, an[6], cn[6], an[7], cn[7]);
        *(uint4*)(sa + (size_t)i*8) = v;
      }
    }
  }
  __syncthreads();
  const int s0 = z*18 + ((w==0) ? 0 : (w==1) ? 6 : (w==2) ? 10 : 14);   // even
  const int h2 = s0 >> 1;
  const int nvalid = (w==0) ? 6 : ((z==2 && w==3) ? 5 : 4);
  floatx4 acc[6][2];
  #pragma unroll
  for (int i = 0; i < 6; ++i){ acc[i][0] = (floatx4)0.f; acc[i][1] = (floatx4)0.f; }
  for (int r = 0; r < 3; ++r){
    short8 af[3][2];
    #pragma unroll
    for (int kw = 0; kw < 3; ++kw)
      #pragma unroll
      for (int mt = 0; mt < 2; ++mt)
        af[kw][mt] = *(const short8*)(fw3 + (((size_t)(r*3+kw)*2 + mt)*64 + L)*8);
    short8 bb[4];
    #pragma unroll
    for (int d = 0; d < 4; ++d){
      const int wi = h2 - 1 + d;
      const int wl = wi - wib;
      short8 v = (short8)0;
      if (wl >= 0 && wl <= 10)
        v = *(const short8*)(sa + (size_t)(r*11 + wl)*512 + L*8);
      bb[d] = v;
    }
    #pragma unroll
    for (int idx = 0; idx < 6; ++idx){
      if (idx >= nvalid) continue;             // wave-uniform
      if ((idx & 1) == 0){
        const int d = idx >> 1;                // kw=0: bb[d], kw=2: bb[d+1]
        #pragma unroll
        for (int mt = 0; mt < 2; ++mt){
          acc[idx][mt] = mfma16(af[0][mt], bb[d],   acc[idx][mt]);
          acc[idx][mt] = mfma16(af[2][mt], bb[d+1], acc[idx][mt]);
        }
      } else {
        const int d = ((idx - 1) >> 1) + 1;    // kw=1
        #pragma unroll
        for (int mt = 0; mt < 2; ++mt)
          acc[idx][mt] = mfma16(af[1][mt], bb[d], acc[idx][mt]);
      }
    }
  }
  const int jj = jL;
  float ss[2][4] = {{0,0,0,0},{0,0,0,0}}, sq[2][4] = {{0,0,0,0},{0,0,0,0}};
  #pragma unroll
  for (int idx = 0; idx < 6; ++idx){
    if (idx >= nvalid) continue;
    #pragma unroll
    for (int mt = 0; mt < 2; ++mt){
      floatx4 a = acc[idx][mt];
      ss[mt][0] += a.x; ss[mt][1] += a.y; ss[mt][2] += a.z; ss[mt][3] += a.w;
      sq[mt][0] += a.x*a.x; sq[mt][1] += a.y*a.y; sq[mt][2] += a.z*a.z; sq[mt][3] += a.w*a.w;
    }
  }
  #pragma unroll
  for (int mt = 0; mt < 2; ++mt)
    #pragma unroll
    for (int r2 = 0; r2 < 4; ++r2){
      float v1 = ss[mt][r2], v2 = sq[mt][r2];
      for (int d = 1; d < 16; d <<= 1){ v1 += __shfl_xor(v1, d, 64); v2 += __shfl_xor(v2, d, 64); }
      if (bL == 0){
        int cch = mt*16 + jj*4 + r2;
        sred[0][w][cch] = v1;
        sred[1][w][cch] = v2;
      }
    }
  __syncthreads();
  if (t < 64){
    const int cch = t & 31, j2 = t >> 5;
    float tot = sred[j2][0][cch] + sred[j2][1][cch] + sred[j2][2][cch] + sred[j2][3][cch];
    const int bid = (z*36 + blockIdx.y)*64 + blockIdx.x;
    ws[(j2 ? P3Q_ABS : P3S_ABS) + bid*32 + cch] = tot;
  }
  unsigned short* st = sa + w*3456;
  #pragma unroll
  for (int idx = 0; idx < 6; ++idx){
    if (idx >= nvalid) continue;
    #pragma unroll
    for (int mt = 0; mt < 2; ++mt){
      floatx4 a = acc[idx][mt];
      uint2 pk;
      pk.x = (unsigned int)f2bu(a.x) | ((unsigned int)f2bu(a.y) << 16);
      pk.y = (unsigned int)f2bu(a.z) | ((unsigned int)f2bu(a.w) << 16);
      *(uint2*)(st + idx*576 + bL*36 + mt*16 + jj*4) = pk;
    }
  }
  const int sb = L >> 2, q2 = L & 3;
  #pragma unroll
  for (int idx = 0; idx < 6; ++idx){
    if (idx >= nvalid) continue;
    const int wo = s0 + idx;
    uint4 v = *(const uint4*)(st + idx*576 + sb*36 + q2*8);
    *(uint4*)(x3 + ((size_t)(ho*55+wo)*1024 + b0 + sb)*32 + q2*8) = v;
  }
}

// ============ deconv4 (MFMA, banded A): x3 -> o4 (B,36,105) ============
__global__ __launch_bounds__(256) void k_dc4(const unsigned short* __restrict__ x3,
                                             const unsigned short* __restrict__ fw4,
                                             float* __restrict__ o4, const float* __restrict__ ws){
  const int t = threadIdx.x;
  const int w = t >> 6, L = t & 63;
  const int b0 = blockIdx.x*16;
  const int ho0 = blockIdx.y*3;
  __shared__ float a3s[32], c3s[32];
  __shared__ unsigned short fa4[30*512];
  __shared__ float rowbuf[16*113];
  if (t < 32){ a3s[t] = ws[OFF_A3+t]; c3s[t] = ws[OFF_C3+t]; }
  for (int i = t; i < 1920; i += 256)
    *(uint4*)(fa4 + (size_t)i*8) = *(const uint4*)(fw4 + (size_t)i*8);
  __syncthreads();
  const int bL = L & 15, jj = (L>>4)&3, ci0 = jj*8;
  float an[8], cn[8];
  #pragma unroll
  for (int e = 0; e < 8; ++e){ an[e] = a3s[ci0+e]; cn[e] = c3s[ci0+e]; }
  floatx4 acc[2][3];
  #pragma unroll
  for (int i = 0; i < 2; ++i)
    #pragma unroll
    for (int h = 0; h < 3; ++h) acc[i][h] = (floatx4)0.f;
  for (int e = 0; e < 5; ++e){               // hi rows, rolled
    const int hi = ho0 - 1 + e;
    if (hi < 0 || hi >= 36) continue;        // uniform
    #pragma unroll
    for (int ts = 0; ts < 2; ++ts){
      const int T = w + ts*4;
      if (T >= 7) continue;                  // uniform
      #pragma unroll 5
      for (int d = 0; d < 10; ++d){
        const int wi = 8*T + d;
        short8 bf;
        if (wi < 55){                        // uniform
          uint4 v = *(const uint4*)(x3 + ((size_t)(hi*55 + wi)*1024 + b0 + bL)*32 + ci0);
          v.x = nrm2(v.x, an[0], cn[0], an[1], cn[1]);
          v.y = nrm2(v.y, an[2], cn[2], an[3], cn[3]);
          v.z = nrm2(v.z, an[4], cn[4], an[5], cn[5]);
          v.w = nrm2(v.w, an[6], cn[6], an[7], cn[7]);
          bf = __builtin_bit_cast(short8, v);
        } else {
          bf = (short8)0;
        }
        #pragma unroll
        for (int hl = 0; hl < 3; ++hl){
          const int r = e - hl;
          if (r < 0 || r > 2) continue;
          short8 af = *(const short8*)(fa4 + ((size_t)(r*10 + d)*64 + L)*8);
          acc[ts][hl] = mfma16(af, bf, acc[ts][hl]);
        }
      }
    }
  }
  #pragma unroll
  for (int hl = 0; hl < 3; ++hl){
    __syncthreads();
    #pragma unroll
    for (int ts = 0; ts < 2; ++ts){
      const int T = w + ts*4;
      if (T >= 7) continue;
      floatx4 a = acc[ts][hl];
      float vals[4] = {a.x, a.y, a.z, a.w};
      #pragma unroll
      for (int reg = 0; reg < 4; ++reg){
        const int wo = 16*T + jj*4 + reg;
        if (wo < 105) rowbuf[bL*113 + wo] = vals[reg];
      }
    }
    __syncthreads();
    const int ho = ho0 + hl;
    for (int i = t; i < 1680; i += 256){
      const int bb = i / 105, wo = i - bb*105;
      o4[(size_t)(b0 + bb)*3780 + ho*105 + wo] = rowbuf[bb*113 + wo];
    }
  }
}

// ============ node softmax / outputs ============
__global__ __launch_bounds__(256) void k_node(const float* __restrict__ o4, float* __restrict__ dout,
                                              float* __restrict__ ws){
  const int t = threadIdx.x;
  const int tg = blockIdx.x*256 + t;
  __shared__ float red[256];
  float lp = 0.f;
  {
    int b = tg / 30, n = tg - b*30;
    const float* p = o4 + (size_t)b*3780 + n*126;
    float l[6]; float mx = -1e30f;
    #pragma unroll
    for (int j = 0; j < 6; ++j){ l[j] = p[j]; mx = fmaxf(mx, l[j]); }
    float e[6]; float s = 0.f;
    #pragma unroll
    for (int j = 0; j < 6; ++j){ e[j] = expf(l[j] - mx); s += e[j]; }
    float inv = 1.f / s;
    int am = 0; float best = e[0];
    #pragma unroll
    for (int j = 1; j < 6; ++j){ if (e[j] > best){ best = e[j]; am = j; } }
    #pragma unroll
    for (int j = 0; j < 5; ++j) dout[OUT0 + (size_t)tg*5 + j] = e[j+1]*inv;
    dout[OUT3 + tg] = 1.f - e[0]*inv;
    #pragma unroll
    for (int j = 0; j < 5; ++j) dout[OUT6 + (size_t)tg*5 + j] = (am == j+1) ? 1.f : 0.f;
    dout[OUT8 + tg] = (am != 0) ? 1.f : 0.f;
    dout[OUT5 + tg] = (float)b;
    lp = logf(best*inv + 1e-7f);
  }
  red[t] = lp; __syncthreads();
  for (int off = 128; off > 0; off >>= 1){ if (t < off) red[t] += red[t+off]; __syncthreads(); }
  if (t == 0) atomicAdd(&ws[OFF_LP], red[0]);
}

// ============ edge softmax / outputs ============
__global__ __launch_bounds__(256) void k_edge(const float* __restrict__ o4, float* __restrict__ dout,
                                              float* __restrict__ ws){
  const int t = threadIdx.x;
  const int tg = blockIdx.x*256 + t;
  __shared__ float red[256];
  float lp = 0.f;
  {
    int b = tg / 435, k = tg - b*435;
    // closed-form triu_indices(30,1): offset(i) = i*(59-i)/2
    int i = (int)((59.0f - sqrtf((float)(3481 - 8*k))) * 0.5f);
    int rem = k - ((i*(59 - i)) >> 1);
    if (rem < 0){ i -= 1; rem = k - ((i*(59 - i)) >> 1); }
    else if (rem >= 29 - i){ rem -= 29 - i; i += 1; }
    int j = i + 1 + rem;
    const float* p = o4 + (size_t)b*3780 + i*126 + 6 + j*4;
    float l0 = p[0], l1 = p[1], l2 = p[2], l3 = p[3];
    float mx = fmaxf(fmaxf(l0, l1), fmaxf(l2, l3));
    float e0 = expf(l0-mx), e1 = expf(l1-mx), e2 = expf(l2-mx), e3 = expf(l3-mx);
    float inv = 1.f / (e0 + e1 + e2 + e3);
    float pr0 = e0*inv, pr1 = e1*inv, pr2 = e2*inv, pr3 = e3*inv;
    int am = 0; float best = pr0;
    if (pr1 > best){ best = pr1; am = 1; }
    if (pr2 > best){ best = pr2; am = 2; }
    if (pr3 > best){ best = pr3; am = 3; }
    size_t e1i = (size_t)b*870 + k, e2i = e1i + 435;
    dout[OUT2 + e1i*3 + 0] = pr1; dout[OUT2 + e1i*3 + 1] = pr2; dout[OUT2 + e1i*3 + 2] = pr3;
    dout[OUT2 + e2i*3 + 0] = pr1; dout[OUT2 + e2i*3 + 1] = pr2; dout[OUT2 + e2i*3 + 2] = pr3;
    dout[OUT4 + e1i] = 1.f - pr0;  dout[OUT4 + e2i] = 1.f - pr0;
    float h1 = (am == 1) ? 1.f : 0.f, h2 = (am == 2) ? 1.f : 0.f, h3 = (am == 3) ? 1.f : 0.f;
    dout[OUT7 + e1i*3 + 0] = h1; dout[OUT7 + e1i*3 + 1] = h2; dout[OUT7 + e1i*3 + 2] = h3;
    dout[OUT7 + e2i*3 + 0] = h1; dout[OUT7 + e2i*3 + 1] = h2; dout[OUT7 + e2i*3 + 2] = h3;
    dout[OUT9 + e1i] = (am != 0) ? 1.f : 0.f;  dout[OUT9 + e2i] = (am != 0) ? 1.f : 0.f;
    if (b == 0){
      dout[OUT1 + k]        = (float)i;
      dout[OUT1 + 435 + k]  = (float)j;
      dout[OUT1 + 870 + k]  = (float)j;
      dout[OUT1 + 1305 + k] = (float)i;
    }
    lp = logf(best + 1e-7f);
  }
  red[t] = lp; __syncthreads();
  for (int off = 128; off > 0; off >>= 1){ if (t < off) red[t] += red[t+off]; __syncthreads(); }
  if (t == 0) atomicAdd(&ws[OFF_LP], red[0]);
}

__global__ void k_lp_copy(float* __restrict__ dout, const float* __restrict__ ws){
  if (threadIdx.x == 0 && blockIdx.x == 0) dout[OUT10] = ws[OFF_LP];
}

extern "C" void kernel_launch(void* const* d_in, const int* in_sizes, int n_in,
                              void* d_out, int out_size, void* d_ws, size_t ws_size,
                              hipStream_t stream) {
  const float* Z  = (const float*)d_in[0];
  const float* W1 = (const float*)d_in[1];
  const float* W2 = (const float*)d_in[2];
  const float* W3 = (const float*)d_in[3];
  const float* W4 = (const float*)d_in[4];
  const float* g1 = (const float*)d_in[5];
  const float* b1 = (const float*)d_in[6];
  const float* g2 = (const float*)d_in[7];
  const float* b2 = (const float*)d_in[8];
  const float* g3 = (const float*)d_in[9];
  const float* b3 = (const float*)d_in[10];

  float* ws  = (float*)d_ws;
  char*  wsb = (char*)d_ws;
  unsigned short* fw2 = (unsigned short*)(wsb + FW2_BYTE);
  unsigned short* fw3 = (unsigned short*)(wsb + FW3_BYTE);
  unsigned short* fw4 = (unsigned short*)(wsb + FW4_BYTE);
  unsigned short* x2u = (unsigned short*)(wsb + X2_BYTE);
  unsigned short* x3u = (unsigned short*)(wsb + X3_BYTE);
  float*          o4  = (float*)(wsb + O4_BYTE);
  float* dout = (float*)d_out;
  (void)in_sizes; (void)n_in; (void)out_size; (void)ws_size;

  k_prep<<<dim3(9), dim3(256), 0, stream>>>(W2, W3, W4, fw2, fw3, fw4);
  k_dc1<<<dim3(1024), dim3(256), 0, stream>>>(Z, W1, ws);
  k_fin<<<dim3(64), dim3(256), 0, stream>>>(ws, g1, b1, OFF_P1S, OFF_P1Q, 1024, 64,
                                            1.f/243712.f, OFF_A1, OFF_C1, 0);
  k2<<<dim3(64, 36), dim3(256), 0, stream>>>(Z, W1, fw2, x2u, ws);
  k_fin<<<dim3(32), dim3(256), 0, stream>>>(ws, g2, b2, OFF_P2S, OFF_P2Q, 2304, 32,
                                            1.f/995328.f, OFF_A2, OFF_C2, 0);
  k3<<<dim3(64, 36, 3), dim3(256), 0, stream>>>(x2u, fw3, x3u, ws);
  k_fin<<<dim3(32), dim3(256), 0, stream>>>(ws, g3, b3, P3S_ABS, P3Q_ABS, 6912, 32,
                                            1.f/2027520.f, OFF_A3, OFF_C3, 1);
  k_dc4<<<dim3(64, 12), dim3(256), 0, stream>>>(x3u, fw4, o4, ws);
  k_node<<<dim3(120), dim3(256), 0, stream>>>(o4, dout, ws);
  k_edge<<<dim3(1740), dim3(256), 0, stream>>>(o4, dout, ws);
  k_lp_copy<<<dim3(1), dim3(64), 0, stream>>>(dout, ws);
}

// Round 8
// 349.774 us; speedup vs baseline: 1.0334x; 1.0334x over previous
//
#include <hip/hip_runtime.h>
#include <hip/hip_bf16.h>

typedef __hip_bfloat16 bf16;
typedef __attribute__((ext_vector_type(8))) short short8;
typedef __attribute__((ext_vector_type(4))) float floatx4;
typedef __bf16 bf16x8 __attribute__((ext_vector_type(8)));

// ---------------- workspace layout ----------------
// float offsets
#define OFF_A1 0
#define OFF_C1 64
#define OFF_A2 128
#define OFF_C2 160
#define OFF_A3 192
#define OFF_C3 224
#define OFF_LP 256
#define OFF_P1S 512
#define OFF_P1Q 66048            // P1S + 1024*64
#define OFF_P2S 131584           // P1Q + 1024*64
#define OFF_P2Q 205312           // P2S + 2304*32

// byte offsets
#define FW2_BYTE 2295808u
#define FW3_BYTE 2332672u        // + 2304*8*2
#define FW4_BYTE 2351104u        // + 1152*8*2 ; fw4: [r3][d10][L64][8] = 30720 B
#define X2_BYTE  33546240u       // x2 (36,27,1024,32) bf16
#define X3_BYTE  97247232u       // x3 (36,55,1024,32) bf16
#define O4_BYTE  227008512u      // o4 (1024,36,105) f32  (also holds BN3 partials pre-dc4)

// BN3 partials live in the o4 region (consumed by fin3 BEFORE k_dc4 writes o4)
#define P3S_ABS 56752128         // O4_BYTE/4
#define P3Q_ABS 56973312         // + room

// ---------------- d_out layout (float offsets) ----------------
#define OUT0 0
#define OUT1 153600
#define OUT2 155340
#define OUT3 2827980
#define OUT4 2858700
#define OUT5 3749580
#define OUT6 3780300
#define OUT7 3933900
#define OUT8 6606540
#define OUT9 6637260
#define OUT10 7528140

__device__ __forceinline__ bf16 f2b(float v){ return __float2bfloat16(v); }
__device__ __forceinline__ unsigned short f2bu(float v){ bf16 h = __float2bfloat16(v); return *(unsigned short*)&h; }

__device__ __forceinline__ floatx4 mfma16(short8 a, short8 b, floatx4 c){
  return __builtin_amdgcn_mfma_f32_16x16x32_bf16(__builtin_bit_cast(bf16x8, a),
                                                 __builtin_bit_cast(bf16x8, b), c, 0, 0, 0);
}

__device__ __forceinline__ unsigned int nrm2(unsigned int u, float a0, float c0, float a1, float c1){
  float x0 = __uint_as_float(u << 16);
  float x1 = __uint_as_float(u & 0xffff0000u);
  float y0 = fmaxf(fmaf(a0, x0, c0), 0.f);
  float y1 = fmaxf(fmaf(a1, x1, c1), 0.f);
  return (unsigned int)f2bu(y0) | ((unsigned int)f2bu(y1) << 16);
}

__device__ __forceinline__ void gload_lds16(const unsigned short* g, unsigned short* lds){
  __builtin_amdgcn_global_load_lds((const __attribute__((address_space(1))) unsigned int*)g,
                                   (__attribute__((address_space(3))) unsigned int*)lds, 16, 0, 0);
}

// ============ weight fragment prep ============
__global__ __launch_bounds__(256) void k_prep(const float* __restrict__ W2, const float* __restrict__ W3,
                                              const float* __restrict__ W4,
                                              unsigned short* __restrict__ fw2, unsigned short* __restrict__ fw3,
                                              unsigned short* __restrict__ fw4){
  const int t = blockIdx.x*256 + threadIdx.x;
  if (t < 2304){   // fw2: [tap9][mt2][kc2][L64][8]
    const int L = t & 63, kc = (t>>6)&1, mt = (t>>7)&1, tap = t>>8;
    const int co = mt*16 + (L&15), ci0 = kc*32 + ((L>>4)&3)*8;
    #pragma unroll
    for (int j = 0; j < 8; ++j)
      fw2[(size_t)t*8 + j] = f2bu(W2[((size_t)tap*64 + ci0 + j)*32 + co]);
  }
  if (t < 1152){   // fw3: [tap9][mt2][L64][8]
    const int L = t & 63, mt = (t>>6)&1, tap = t>>7;
    const int co = mt*16 + (L&15), ci0 = ((L>>4)&3)*8;
    #pragma unroll
    for (int j = 0; j < 8; ++j)
      fw3[(size_t)t*8 + j] = f2bu(W3[((size_t)tap*32 + ci0 + j)*32 + co]);
  }
  if (t < 1920){   // fw4: banded layer-4 A-frags [r3][d10][L64][8]; A[m][ci] = W4[r][kw=2d-m][ci]
    const int L = t & 63, d = (t>>6) % 10, r = t / 640;
    const int m = L & 15, ci0 = ((L>>4)&3)*8;
    const int kw = 2*d - m;
    #pragma unroll
    for (int j = 0; j < 8; ++j)
      fw4[(size_t)t*8 + j] = (kw >= 0 && kw < 5) ? f2bu(W4[(r*5 + kw)*32 + ci0 + j])
                                                 : (unsigned short)0;
  }
}

// ============ layer-1 stats only ============
__global__ __launch_bounds__(256) void k_dc1(const float* __restrict__ Z, const float* __restrict__ W1,
                                             float* __restrict__ ws){
  const int b = blockIdx.x, t = threadIdx.x;
  __shared__ float zs[32];
  __shared__ float w1s[3*7*64];
  __shared__ float red[256];
  if (t < 32) zs[t] = Z[b*32 + t];
  for (int i = t; i < 1344; i += 256) w1s[i] = W1[i];
  __syncthreads();
  float lsum = 0.f, lsq = 0.f;
  for (int idx = t; idx < 15232; idx += 256){
    int co = idx & 63;
    int wo = (idx >> 6) % 7;
    int ho = idx / 448;
    int kw = 6 - wo;
    float y = 0.f;
    #pragma unroll
    for (int kh = 0; kh < 3; ++kh){
      int hi = ho + kh - 2;
      if (hi >= 0 && hi < 32) y += zs[hi] * w1s[(kh*7 + kw)*64 + co];
    }
    lsum += y; lsq += y*y;
  }
  red[t] = lsum; __syncthreads();
  if (t < 64) ws[OFF_P1S + b*64 + t] = red[t] + red[t+64] + red[t+128] + red[t+192];
  __syncthreads();
  red[t] = lsq; __syncthreads();
  if (t < 64) ws[OFF_P1Q + b*64 + t] = red[t] + red[t+64] + red[t+128] + red[t+192];
}

// ============ BN finalize: partials laid out [part][nch] ============
__global__ __launch_bounds__(256) void k_fin(float* __restrict__ ws, const float* __restrict__ g,
                                             const float* __restrict__ bb, int ps, int pq, int npart,
                                             int nch, float inv_n, int ao, int co, int zlp){
  const int c = blockIdx.x, t = threadIdx.x;
  __shared__ float r1[256], r2[256];
  float s = 0.f, q = 0.f;
  for (int i = t; i < npart; i += 256){ s += ws[ps + i*nch + c]; q += ws[pq + i*nch + c]; }
  r1[t] = s; r2[t] = q; __syncthreads();
  for (int off = 128; off > 0; off >>= 1){
    if (t < off){ r1[t] += r1[t+off]; r2[t] += r2[t+off]; }
    __syncthreads();
  }
  if (t == 0){
    float m  = r1[0] * inv_n;
    float v  = r2[0] * inv_n - m*m;
    float is = rsqrtf(v + 1e-5f);
    float a  = g[c] * is;
    ws[ao + c] = a;
    ws[co + c] = bb[c] - a*m;
  }
  if (zlp && c == 0 && t == 0) ws[OFF_LP] = 0.f;
}

// ============ deconv2 (MFMA): Z -> (recompute act1) -> x2 (36,27,1024,32) ============
__global__ __launch_bounds__(256) void k2(const float* __restrict__ Z, const float* __restrict__ W1,
                                          const unsigned short* __restrict__ fw2,
                                          unsigned short* __restrict__ x2, float* __restrict__ ws){
  const int t = threadIdx.x;
  const int b0 = blockIdx.x*16, ho = blockIdx.y;
  __shared__ unsigned short sa[21*1024];
  __shared__ float zs[16][32];
  __shared__ float w1s[1344];
  __shared__ float sa1[64], sc1[64];
  __shared__ float sred[2][4][32];
  if (t < 64){ sa1[t] = ws[OFF_A1+t]; sc1[t] = ws[OFF_C1+t]; }
  for (int i = t; i < 512; i += 256) zs[i>>5][i&31] = Z[(b0 + (i>>5))*32 + (i&31)];
  for (int i = t; i < 1344; i += 256) w1s[i] = W1[i];
  __syncthreads();
  for (int c = t; c < 21*128; c += 256){
    const int p = c >> 7, g = c & 127;
    const int r = p/7, wi = p - r*7;
    const int hi = ho - 2 + r;
    const int b = g >> 3, kc = (g >> 2) & 1, j = g & 3;
    const int ci0 = kc*32 + j*8;
    unsigned int pk[4] = {0,0,0,0};
    if (hi >= 0 && hi < 34){
      const float* wp = &w1s[(6 - wi)*64 + ci0];
      #pragma unroll
      for (int e = 0; e < 8; e += 2){
        float y0 = 0.f, y1 = 0.f;
        #pragma unroll
        for (int kh = 0; kh < 3; ++kh){
          const int q = hi + kh - 2;
          if (q >= 0 && q < 32){
            float zv = zs[b][q];
            y0 += zv * wp[kh*448 + e];
            y1 += zv * wp[kh*448 + e + 1];
          }
        }
        float u0 = fmaxf(fmaf(sa1[ci0+e],   y0, sc1[ci0+e]),   0.f);
        float u1 = fmaxf(fmaf(sa1[ci0+e+1], y1, sc1[ci0+e+1]), 0.f);
        pk[e>>1] = (unsigned int)f2bu(u0) | ((unsigned int)f2bu(u1) << 16);
      }
    }
    *(uint4*)(sa + (size_t)p*1024 + kc*512 + (j*16 + b)*8) = *(uint4*)pk;
  }
  __syncthreads();
  const int w = t>>6, L = t&63;
  floatx4 acc[8][2];
  #pragma unroll
  for (int i = 0; i < 8; ++i){ acc[i][0] = (floatx4)0.f; acc[i][1] = (floatx4)0.f; }
  const int wiA = 2*w, wiB = (w < 3) ? 2*w + 1 : 2*w;
  for (int r = 0; r < 3; ++r){
    short8 af[3][2][2];
    #pragma unroll
    for (int kw = 0; kw < 3; ++kw)
      #pragma unroll
      for (int mt = 0; mt < 2; ++mt)
        #pragma unroll
        for (int kc = 0; kc < 2; ++kc)
          af[kw][mt][kc] = *(const short8*)(fw2 + ((((size_t)(r*3+kw)*2 + mt)*2 + kc)*64 + L)*8);
    const short8* pA = (const short8*)(sa + (size_t)(r*7 + wiA)*1024);
    const short8* pB = (const short8*)(sa + (size_t)(r*7 + wiB)*1024);
    short8 fa0 = pA[L], fa1 = pA[64+L];
    short8 fb0 = pB[L], fb1 = pB[64+L];
    #pragma unroll
    for (int idx = 0; idx < 8; ++idx){
      if (idx == 3 || idx == 7) continue;
      const int kw = (2 - idx) & 3;
      const int half = idx >> 2;
      if (half && w == 3) continue;
      short8 f0 = half ? fb0 : fa0;
      short8 f1 = half ? fb1 : fa1;
      #pragma unroll
      for (int mt = 0; mt < 2; ++mt){
        acc[idx][mt] = mfma16(af[kw][mt][0], f0, acc[idx][mt]);
        acc[idx][mt] = mfma16(af[kw][mt][1], f1, acc[idx][mt]);
      }
    }
  }
  const int bL = L & 15, jj = (L>>4)&3;
  float ss[2][4] = {{0,0,0,0},{0,0,0,0}}, sq[2][4] = {{0,0,0,0},{0,0,0,0}};
  #pragma unroll
  for (int idx = 0; idx < 8; ++idx){
    if (8*w + idx >= 27) continue;
    #pragma unroll
    for (int mt = 0; mt < 2; ++mt){
      floatx4 a = acc[idx][mt];
      ss[mt][0] += a.x; ss[mt][1] += a.y; ss[mt][2] += a.z; ss[mt][3] += a.w;
      sq[mt][0] += a.x*a.x; sq[mt][1] += a.y*a.y; sq[mt][2] += a.z*a.z; sq[mt][3] += a.w*a.w;
    }
  }
  #pragma unroll
  for (int mt = 0; mt < 2; ++mt)
    #pragma unroll
    for (int r2 = 0; r2 < 4; ++r2){
      float v1 = ss[mt][r2], v2 = sq[mt][r2];
      for (int d = 1; d < 16; d <<= 1){ v1 += __shfl_xor(v1, d, 64); v2 += __shfl_xor(v2, d, 64); }
      if (bL == 0){
        int cch = mt*16 + jj*4 + r2;
        sred[0][w][cch] = v1;
        sred[1][w][cch] = v2;
      }
    }
  __syncthreads();
  if (t < 64){
    const int cch = t & 31, j2 = t >> 5;
    float tot = sred[j2][0][cch] + sred[j2][1][cch] + sred[j2][2][cch] + sred[j2][3][cch];
    const int bid = blockIdx.y*64 + blockIdx.x;
    ws[(j2 ? OFF_P2Q : OFF_P2S) + bid*32 + cch] = tot;
  }
  unsigned short* st = sa + w*4608;
  #pragma unroll
  for (int idx = 0; idx < 8; ++idx){
    if (8*w + idx >= 27) continue;
    #pragma unroll
    for (int mt = 0; mt < 2; ++mt){
      floatx4 a = acc[idx][mt];
      uint2 pk;
      pk.x = (unsigned int)f2bu(a.x) | ((unsigned int)f2bu(a.y) << 16);
      pk.y = (unsigned int)f2bu(a.z) | ((unsigned int)f2bu(a.w) << 16);
      *(uint2*)(st + idx*576 + bL*36 + mt*16 + jj*4) = pk;
    }
  }
  const int sb = L >> 2, q2 = L & 3;
  #pragma unroll
  for (int idx = 0; idx < 8; ++idx){
    const int wo = 8*w + idx;
    if (wo >= 27) continue;
    uint4 v = *(const uint4*)(st + idx*576 + sb*36 + q2*8);
    *(uint4*)(x2 + ((size_t)(ho*27+wo)*1024 + b0 + sb)*32 + q2*8) = v;
  }
}

// ============ deconv3 (MFMA, DMA-staged, ho-pair): x2 -> x3 (36,55,1024,32) ============
// 2 output rows per block: stage 4 hi rows x 11 wi via global_load_lds (lane-indexed frag
// order), in-LDS BN+ReLU RMW, then per-row MFMA with static tap parity. 3-way wo split.
__global__ __launch_bounds__(256) void k3(const unsigned short* __restrict__ x2, const unsigned short* __restrict__ fw3,
                                          unsigned short* __restrict__ x3, float* __restrict__ ws){
  const int t = threadIdx.x;
  const int b0 = blockIdx.x*16, hop = blockIdx.y, z = blockIdx.z;
  const int ho0 = hop*2;
  const int wib = (z == 0) ? 0 : ((z == 1) ? 8 : 17);
  __shared__ unsigned short sa[44*512];      // 4r x 11wi pixels, lane-indexed; reused as store buffer
  __shared__ float sa2[32], sc2[32];
  __shared__ float sred[2][4][32];
  if (t < 32){ sa2[t] = ws[OFF_A2+t]; sc2[t] = ws[OFF_C2+t]; }
  const int w = t>>6, L = t&63;
  const int bL = L & 15, jL = (L>>4)&3, ci0 = jL*8;
  // async DMA staging: lane L fetches chunk (b=bL, ci-group=jL) -> LDS lane slot L*16B
  for (int p = w; p < 44; p += 4){
    const int row = p/11, wl = p - row*11;
    const int hi = ho0 - 1 + row, wi = wib + wl;
    unsigned short* dst = sa + p*512;
    if (hi >= 0 && hi < 36 && wi < 27){
      const unsigned short* src = x2 + ((size_t)(hi*27 + wi)*1024 + b0 + bL)*32 + ci0;
      gload_lds16(src, dst);
    } else {
      *(uint4*)(dst + L*8) = make_uint4(0,0,0,0);
    }
  }
  __syncthreads();
  // in-LDS BN+ReLU (invalid pixels stay zero); i%64==t%64 so (b,j) matches this lane's an/cn
  {
    float an[8], cn[8];
    #pragma unroll
    for (int e = 0; e < 8; ++e){ an[e] = sa2[ci0+e]; cn[e] = sc2[ci0+e]; }
    for (int i = t; i < 44*64; i += 256){
      const int p = i >> 6;                    // wave-uniform
      const int row = p/11, wl = p - row*11;
      const int hi = ho0 - 1 + row, wi = wib + wl;
      if (hi >= 0 && hi < 36 && wi < 27){
        uint4 v = *(uint4*)(sa + (size_t)i*8);
        v.x = nrm2(v.x, an[0], cn[0], an[1], cn[1]);
        v.y = nrm2(v.y, an[2], cn[2], an[3], cn[3]);
        v.z = nrm2(v.z, an[4], cn[4], an[5], cn[5]);
        v.w = nrm2(v.w, an[6], cn[6], an[7], cn[7]);
        *(uint4*)(sa + (size_t)i*8) = v;
      }
    }
  }
  __syncthreads();
  const int s0 = z*18 + ((w==0) ? 0 : (w==1) ? 6 : (w==2) ? 10 : 14);   // even
  const int h2 = s0 >> 1;
  const int nvalid = (w==0) ? 6 : ((z==2 && w==3) ? 5 : 4);
  floatx4 acc[2][6][2];
  #pragma unroll
  for (int hoL = 0; hoL < 2; ++hoL)
    #pragma unroll
    for (int i = 0; i < 6; ++i){ acc[hoL][i][0] = (floatx4)0.f; acc[hoL][i][1] = (floatx4)0.f; }
  for (int r = 0; r < 3; ++r){
    short8 af[3][2];
    #pragma unroll
    for (int kw = 0; kw < 3; ++kw)
      #pragma unroll
      for (int mt = 0; mt < 2; ++mt)
        af[kw][mt] = *(const short8*)(fw3 + (((size_t)(r*3+kw)*2 + mt)*64 + L)*8);
    #pragma unroll
    for (int hoL = 0; hoL < 2; ++hoL){
      const int row = hoL + r;                 // staged row index 0..3
      short8 bb[4];
      #pragma unroll
      for (int d = 0; d < 4; ++d){
        const int wl = h2 - 1 + d - wib;
        short8 v = (short8)0;
        if (wl >= 0 && wl <= 10)
          v = *(const short8*)(sa + (size_t)(row*11 + wl)*512 + L*8);
        bb[d] = v;
      }
      #pragma unroll
      for (int idx = 0; idx < 6; ++idx){
        if (idx >= nvalid) continue;           // wave-uniform
        if ((idx & 1) == 0){
          const int d = idx >> 1;              // kw=0: bb[d], kw=2: bb[d+1]
          #pragma unroll
          for (int mt = 0; mt < 2; ++mt){
            acc[hoL][idx][mt] = mfma16(af[0][mt], bb[d],   acc[hoL][idx][mt]);
            acc[hoL][idx][mt] = mfma16(af[2][mt], bb[d+1], acc[hoL][idx][mt]);
          }
        } else {
          const int d = ((idx - 1) >> 1) + 1;  // kw=1
          #pragma unroll
          for (int mt = 0; mt < 2; ++mt)
            acc[hoL][idx][mt] = mfma16(af[1][mt], bb[d], acc[hoL][idx][mt]);
        }
      }
    }
  }
  const int jj = jL;
  float ss[2][4] = {{0,0,0,0},{0,0,0,0}}, sq[2][4] = {{0,0,0,0},{0,0,0,0}};
  #pragma unroll
  for (int hoL = 0; hoL < 2; ++hoL)
    #pragma unroll
    for (int idx = 0; idx < 6; ++idx){
      if (idx >= nvalid) continue;
      #pragma unroll
      for (int mt = 0; mt < 2; ++mt){
        floatx4 a = acc[hoL][idx][mt];
        ss[mt][0] += a.x; ss[mt][1] += a.y; ss[mt][2] += a.z; ss[mt][3] += a.w;
        sq[mt][0] += a.x*a.x; sq[mt][1] += a.y*a.y; sq[mt][2] += a.z*a.z; sq[mt][3] += a.w*a.w;
      }
    }
  #pragma unroll
  for (int mt = 0; mt < 2; ++mt)
    #pragma unroll
    for (int r2 = 0; r2 < 4; ++r2){
      float v1 = ss[mt][r2], v2 = sq[mt][r2];
      for (int d = 1; d < 16; d <<= 1){ v1 += __shfl_xor(v1, d, 64); v2 += __shfl_xor(v2, d, 64); }
      if (bL == 0){
        int cch = mt*16 + jj*4 + r2;
        sred[0][w][cch] = v1;
        sred[1][w][cch] = v2;
      }
    }
  __syncthreads();                             // also: all MFMA reads of sa done
  if (t < 64){
    const int cch = t & 31, j2 = t >> 5;
    float tot = sred[j2][0][cch] + sred[j2][1][cch] + sred[j2][2][cch] + sred[j2][3][cch];
    const int bid = (z*18 + hop)*64 + blockIdx.x;
    ws[(j2 ? P3Q_ABS : P3S_ABS) + bid*32 + cch] = tot;
  }
  unsigned short* st = sa + w*3456;            // wave-private pack buffer
  const int sb = L >> 2, q2 = L & 3;
  #pragma unroll
  for (int hoL = 0; hoL < 2; ++hoL){
    #pragma unroll
    for (int idx = 0; idx < 6; ++idx){
      if (idx >= nvalid) continue;
      #pragma unroll
      for (int mt = 0; mt < 2; ++mt){
        floatx4 a = acc[hoL][idx][mt];
        uint2 pk;
        pk.x = (unsigned int)f2bu(a.x) | ((unsigned int)f2bu(a.y) << 16);
        pk.y = (unsigned int)f2bu(a.z) | ((unsigned int)f2bu(a.w) << 16);
        *(uint2*)(st + idx*576 + bL*36 + mt*16 + jj*4) = pk;
      }
    }
    #pragma unroll
    for (int idx = 0; idx < 6; ++idx){
      if (idx >= nvalid) continue;
      const int wo = s0 + idx;
      uint4 v = *(const uint4*)(st + idx*576 + sb*36 + q2*8);
      *(uint4*)(x3 + ((size_t)((ho0+hoL)*55+wo)*1024 + b0 + sb)*32 + q2*8) = v;
    }
  }
}

// ============ deconv4 (MFMA, banded A): x3 -> o4 (B,36,105) ============
__global__ __launch_bounds__(256) void k_dc4(const unsigned short* __restrict__ x3,
                                             const unsigned short* __restrict__ fw4,
                                             float* __restrict__ o4, const float* __restrict__ ws){
  const int t = threadIdx.x;
  const int w = t >> 6, L = t & 63;
  const int b0 = blockIdx.x*16;
  const int ho0 = blockIdx.y*3;
  __shared__ float a3s[32], c3s[32];
  __shared__ unsigned short fa4[30*512];
  __shared__ float rowbuf[16*113];
  if (t < 32){ a3s[t] = ws[OFF_A3+t]; c3s[t] = ws[OFF_C3+t]; }
  for (int i = t; i < 1920; i += 256)
    *(uint4*)(fa4 + (size_t)i*8) = *(const uint4*)(fw4 + (size_t)i*8);
  __syncthreads();
  const int bL = L & 15, jj = (L>>4)&3, ci0 = jj*8;
  float an[8], cn[8];
  #pragma unroll
  for (int e = 0; e < 8; ++e){ an[e] = a3s[ci0+e]; cn[e] = c3s[ci0+e]; }
  floatx4 acc[2][3];
  #pragma unroll
  for (int i = 0; i < 2; ++i)
    #pragma unroll
    for (int h = 0; h < 3; ++h) acc[i][h] = (floatx4)0.f;
  for (int e = 0; e < 5; ++e){
    const int hi = ho0 - 1 + e;
    if (hi < 0 || hi >= 36) continue;
    #pragma unroll
    for (int ts = 0; ts < 2; ++ts){
      const int T = w + ts*4;
      if (T >= 7) continue;
      #pragma unroll 5
      for (int d = 0; d < 10; ++d){
        const int wi = 8*T + d;
        short8 bf;
        if (wi < 55){
          uint4 v = *(const uint4*)(x3 + ((size_t)(hi*55 + wi)*1024 + b0 + bL)*32 + ci0);
          v.x = nrm2(v.x, an[0], cn[0], an[1], cn[1]);
          v.y = nrm2(v.y, an[2], cn[2], an[3], cn[3]);
          v.z = nrm2(v.z, an[4], cn[4], an[5], cn[5]);
          v.w = nrm2(v.w, an[6], cn[6], an[7], cn[7]);
          bf = __builtin_bit_cast(short8, v);
        } else {
          bf = (short8)0;
        }
        #pragma unroll
        for (int hl = 0; hl < 3; ++hl){
          const int r = e - hl;
          if (r < 0 || r > 2) continue;
          short8 af = *(const short8*)(fa4 + ((size_t)(r*10 + d)*64 + L)*8);
          acc[ts][hl] = mfma16(af, bf, acc[ts][hl]);
        }
      }
    }
  }
  #pragma unroll
  for (int hl = 0; hl < 3; ++hl){
    __syncthreads();
    #pragma unroll
    for (int ts = 0; ts < 2; ++ts){
      const int T = w + ts*4;
      if (T >= 7) continue;
      floatx4 a = acc[ts][hl];
      float vals[4] = {a.x, a.y, a.z, a.w};
      #pragma unroll
      for (int reg = 0; reg < 4; ++reg){
        const int wo = 16*T + jj*4 + reg;
        if (wo < 105) rowbuf[bL*113 + wo] = vals[reg];
      }
    }
    __syncthreads();
    const int ho = ho0 + hl;
    for (int i = t; i < 1680; i += 256){
      const int bb = i / 105, wo = i - bb*105;
      o4[(size_t)(b0 + bb)*3780 + ho*105 + wo] = rowbuf[bb*113 + wo];
    }
  }
}

// ============ node softmax / outputs ============
__global__ __launch_bounds__(256) void k_node(const float* __restrict__ o4, float* __restrict__ dout,
                                              float* __restrict__ ws){
  const int t = threadIdx.x;
  const int tg = blockIdx.x*256 + t;
  __shared__ float red[256];
  float lp = 0.f;
  {
    int b = tg / 30, n = tg - b*30;
    const float* p = o4 + (size_t)b*3780 + n*126;
    float l[6]; float mx = -1e30f;
    #pragma unroll
    for (int j = 0; j < 6; ++j){ l[j] = p[j]; mx = fmaxf(mx, l[j]); }
    float e[6]; float s = 0.f;
    #pragma unroll
    for (int j = 0; j < 6; ++j){ e[j] = expf(l[j] - mx); s += e[j]; }
    float inv = 1.f / s;
    int am = 0; float best = e[0];
    #pragma unroll
    for (int j = 1; j < 6; ++j){ if (e[j] > best){ best = e[j]; am = j; } }
    #pragma unroll
    for (int j = 0; j < 5; ++j) dout[OUT0 + (size_t)tg*5 + j] = e[j+1]*inv;
    dout[OUT3 + tg] = 1.f - e[0]*inv;
    #pragma unroll
    for (int j = 0; j < 5; ++j) dout[OUT6 + (size_t)tg*5 + j] = (am == j+1) ? 1.f : 0.f;
    dout[OUT8 + tg] = (am != 0) ? 1.f : 0.f;
    dout[OUT5 + tg] = (float)b;
    lp = logf(best*inv + 1e-7f);
  }
  red[t] = lp; __syncthreads();
  for (int off = 128; off > 0; off >>= 1){ if (t < off) red[t] += red[t+off]; __syncthreads(); }
  if (t == 0) atomicAdd(&ws[OFF_LP], red[0]);
}

// ============ edge softmax / outputs ============
__global__ __launch_bounds__(256) void k_edge(const float* __restrict__ o4, float* __restrict__ dout,
                                              float* __restrict__ ws){
  const int t = threadIdx.x;
  const int tg = blockIdx.x*256 + t;
  __shared__ float red[256];
  float lp = 0.f;
  {
    int b = tg / 435, k = tg - b*435;
    // closed-form triu_indices(30,1): offset(i) = i*(59-i)/2
    int i = (int)((59.0f - sqrtf((float)(3481 - 8*k))) * 0.5f);
    int rem = k - ((i*(59 - i)) >> 1);
    if (rem < 0){ i -= 1; rem = k - ((i*(59 - i)) >> 1); }
    else if (rem >= 29 - i){ rem -= 29 - i; i += 1; }
    int j = i + 1 + rem;
    const float* p = o4 + (size_t)b*3780 + i*126 + 6 + j*4;
    float l0 = p[0], l1 = p[1], l2 = p[2], l3 = p[3];
    float mx = fmaxf(fmaxf(l0, l1), fmaxf(l2, l3));
    float e0 = expf(l0-mx), e1 = expf(l1-mx), e2 = expf(l2-mx), e3 = expf(l3-mx);
    float inv = 1.f / (e0 + e1 + e2 + e3);
    float pr0 = e0*inv, pr1 = e1*inv, pr2 = e2*inv, pr3 = e3*inv;
    int am = 0; float best = pr0;
    if (pr1 > best){ best = pr1; am = 1; }
    if (pr2 > best){ best = pr2; am = 2; }
    if (pr3 > best){ best = pr3; am = 3; }
    size_t e1i = (size_t)b*870 + k, e2i = e1i + 435;
    dout[OUT2 + e1i*3 + 0] = pr1; dout[OUT2 + e1i*3 + 1] = pr2; dout[OUT2 + e1i*3 + 2] = pr3;
    dout[OUT2 + e2i*3 + 0] = pr1; dout[OUT2 + e2i*3 + 1] = pr2; dout[OUT2 + e2i*3 + 2] = pr3;
    dout[OUT4 + e1i] = 1.f - pr0;  dout[OUT4 + e2i] = 1.f - pr0;
    float h1 = (am == 1) ? 1.f : 0.f, h2 = (am == 2) ? 1.f : 0.f, h3 = (am == 3) ? 1.f : 0.f;
    dout[OUT7 + e1i*3 + 0] = h1; dout[OUT7 + e1i*3 + 1] = h2; dout[OUT7 + e1i*3 + 2] = h3;
    dout[OUT7 + e2i*3 + 0] = h1; dout[OUT7 + e2i*3 + 1] = h2; dout[OUT7 + e2i*3 + 2] = h3;
    dout[OUT9 + e1i] = (am != 0) ? 1.f : 0.f;  dout[OUT9 + e2i] = (am != 0) ? 1.f : 0.f;
    if (b == 0){
      dout[OUT1 + k]        = (float)i;
      dout[OUT1 + 435 + k]  = (float)j;
      dout[OUT1 + 870 + k]  = (float)j;
      dout[OUT1 + 1305 + k] = (float)i;
    }
    lp = logf(best + 1e-7f);
  }
  red[t] = lp; __syncthreads();
  for (int off = 128; off > 0; off >>= 1){ if (t < off) red[t] += red[t+off]; __syncthreads(); }
  if (t == 0) atomicAdd(&ws[OFF_LP], red[0]);
}

__global__ void k_lp_copy(float* __restrict__ dout, const float* __restrict__ ws){
  if (threadIdx.x == 0 && blockIdx.x == 0) dout[OUT10] = ws[OFF_LP];
}

extern "C" void kernel_launch(void* const* d_in, const int* in_sizes, int n_in,
                              void* d_out, int out_size, void* d_ws, size_t ws_size,
                              hipStream_t stream) {
  const float* Z  = (const float*)d_in[0];
  const float* W1 = (const float*)d_in[1];
  const float* W2 = (const float*)d_in[2];
  const float* W3 = (const float*)d_in[3];
  const float* W4 = (const float*)d_in[4];
  const float* g1 = (const float*)d_in[5];
  const float* b1 = (const float*)d_in[6];
  const float* g2 = (const float*)d_in[7];
  const float* b2 = (const float*)d_in[8];
  const float* g3 = (const float*)d_in[9];
  const float* b3 = (const float*)d_in[10];

  float* ws  = (float*)d_ws;
  char*  wsb = (char*)d_ws;
  unsigned short* fw2 = (unsigned short*)(wsb + FW2_BYTE);
  unsigned short* fw3 = (unsigned short*)(wsb + FW3_BYTE);
  unsigned short* fw4 = (unsigned short*)(wsb + FW4_BYTE);
  unsigned short* x2u = (unsigned short*)(wsb + X2_BYTE);
  unsigned short* x3u = (unsigned short*)(wsb + X3_BYTE);
  float*          o4  = (float*)(wsb + O4_BYTE);
  float* dout = (float*)d_out;
  (void)in_sizes; (void)n_in; (void)out_size; (void)ws_size;

  k_prep<<<dim3(9), dim3(256), 0, stream>>>(W2, W3, W4, fw2, fw3, fw4);
  k_dc1<<<dim3(1024), dim3(256), 0, stream>>>(Z, W1, ws);
  k_fin<<<dim3(64), dim3(256), 0, stream>>>(ws, g1, b1, OFF_P1S, OFF_P1Q, 1024, 64,
                                            1.f/243712.f, OFF_A1, OFF_C1, 0);
  k2<<<dim3(64, 36), dim3(256), 0, stream>>>(Z, W1, fw2, x2u, ws);
  k_fin<<<dim3(32), dim3(256), 0, stream>>>(ws, g2, b2, OFF_P2S, OFF_P2Q, 2304, 32,
                                            1.f/995328.f, OFF_A2, OFF_C2, 0);
  k3<<<dim3(64, 18, 3), dim3(256), 0, stream>>>(x2u, fw3, x3u, ws);
  k_fin<<<dim3(32), dim3(256), 0, stream>>>(ws, g3, b3, P3S_ABS, P3Q_ABS, 3456, 32,
                                            1.f/2027520.f, OFF_A3, OFF_C3, 1);
  k_dc4<<<dim3(64, 12), dim3(256), 0, stream>>>(x3u, fw4, o4, ws);
  k_node<<<dim3(120), dim3(256), 0, stream>>>(o4, dout, ws);
  k_edge<<<dim3(1740), dim3(256), 0, stream>>>(o4, dout, ws);
  k_lp_copy<<<dim3(1), dim3(64), 0, stream>>>(dout, ws);
}

// Round 11
// 331.818 us; speedup vs baseline: 1.0893x; 1.0541x over previous
//
#include <hip/hip_runtime.h>
#include <hip/hip_bf16.h>

typedef __hip_bfloat16 bf16;
typedef __attribute__((ext_vector_type(8))) short short8;
typedef __attribute__((ext_vector_type(4))) float floatx4;
typedef __bf16 bf16x8 __attribute__((ext_vector_type(8)));

// ---------------- workspace layout ----------------
// float offsets
#define OFF_A1 0
#define OFF_C1 64
#define OFF_A2 128
#define OFF_C2 160
#define OFF_A3 192
#define OFF_C3 224
#define OFF_LP 256
#define OFF_P1S 512
#define OFF_P1Q 66048            // P1S + 1024*64
#define OFF_P2S 131584           // P1Q + 1024*64
#define OFF_P2Q 205312           // P2S + 2304*32

// byte offsets
#define FW2_BYTE 2295808u
#define FW3_BYTE 2332672u        // + 2304*8*2
#define FW4_BYTE 2351104u        // + 1152*8*2 ; fw4: [r3][d10][L64][8] = 30720 B
#define X2_BYTE  33546240u       // x2 (36,27,1024,32) bf16
#define X3_BYTE  97247232u       // x3 (36,55,1024,32) bf16
#define O4_BYTE  227008512u      // o4 (1024,36,105) f32  (also holds BN3 partials pre-dc4)

// act1n (normalized act1, frag order): 238 pixels x 64 bg x 1024 shorts = 31.2 MB.
// Aliases the x3 region: consumed by k2 strictly BEFORE k3 writes x3.
#define A1N_BYTE X3_BYTE

// BN3 partials live in the o4 region (consumed by fin3 BEFORE k_dc4 writes o4)
#define P3S_ABS 56752128         // O4_BYTE/4
#define P3Q_ABS 56973312         // + room

// ---------------- d_out layout (float offsets) ----------------
#define OUT0 0
#define OUT1 153600
#define OUT2 155340
#define OUT3 2827980
#define OUT4 2858700
#define OUT5 3749580
#define OUT6 3780300
#define OUT7 3933900
#define OUT8 6606540
#define OUT9 6637260
#define OUT10 7528140

__device__ __forceinline__ bf16 f2b(float v){ return __float2bfloat16(v); }
__device__ __forceinline__ unsigned short f2bu(float v){ bf16 h = __float2bfloat16(v); return *(unsigned short*)&h; }

__device__ __forceinline__ floatx4 mfma16(short8 a, short8 b, floatx4 c){
  return __builtin_amdgcn_mfma_f32_16x16x32_bf16(__builtin_bit_cast(bf16x8, a),
                                                 __builtin_bit_cast(bf16x8, b), c, 0, 0, 0);
}

__device__ __forceinline__ unsigned int nrm2(unsigned int u, float a0, float c0, float a1, float c1){
  float x0 = __uint_as_float(u << 16);
  float x1 = __uint_as_float(u & 0xffff0000u);
  float y0 = fmaxf(fmaf(a0, x0, c0), 0.f);
  float y1 = fmaxf(fmaf(a1, x1, c1), 0.f);
  return (unsigned int)f2bu(y0) | ((unsigned int)f2bu(y1) << 16);
}

__device__ __forceinline__ void gload_lds16(const unsigned short* g, unsigned short* lds){
  __builtin_amdgcn_global_load_lds((const __attribute__((address_space(1))) unsigned int*)g,
                                   (__attribute__((address_space(3))) unsigned int*)lds, 16, 0, 0);
}

// ============ weight fragment prep ============
__global__ __launch_bounds__(256) void k_prep(const float* __restrict__ W2, const float* __restrict__ W3,
                                              const float* __restrict__ W4,
                                              unsigned short* __restrict__ fw2, unsigned short* __restrict__ fw3,
                                              unsigned short* __restrict__ fw4){
  const int t = blockIdx.x*256 + threadIdx.x;
  if (t < 2304){   // fw2: [tap9][mt2][kc2][L64][8]
    const int L = t & 63, kc = (t>>6)&1, mt = (t>>7)&1, tap = t>>8;
    const int co = mt*16 + (L&15), ci0 = kc*32 + ((L>>4)&3)*8;
    #pragma unroll
    for (int j = 0; j < 8; ++j)
      fw2[(size_t)t*8 + j] = f2bu(W2[((size_t)tap*64 + ci0 + j)*32 + co]);
  }
  if (t < 1152){   // fw3: [tap9][mt2][L64][8]
    const int L = t & 63, mt = (t>>6)&1, tap = t>>7;
    const int co = mt*16 + (L&15), ci0 = ((L>>4)&3)*8;
    #pragma unroll
    for (int j = 0; j < 8; ++j)
      fw3[(size_t)t*8 + j] = f2bu(W3[((size_t)tap*32 + ci0 + j)*32 + co]);
  }
  if (t < 1920){   // fw4: banded layer-4 A-frags [r3][d10][L64][8]; A[m][ci] = W4[r][kw=2d-m][ci]
    const int L = t & 63, d = (t>>6) % 10, r = t / 640;
    const int m = L & 15, ci0 = ((L>>4)&3)*8;
    const int kw = 2*d - m;
    #pragma unroll
    for (int j = 0; j < 8; ++j)
      fw4[(size_t)t*8 + j] = (kw >= 0 && kw < 5) ? f2bu(W4[(r*5 + kw)*32 + ci0 + j])
                                                 : (unsigned short)0;
  }
}

// ============ layer-1 stats only ============
__global__ __launch_bounds__(256) void k_dc1(const float* __restrict__ Z, const float* __restrict__ W1,
                                             float* __restrict__ ws){
  const int b = blockIdx.x, t = threadIdx.x;
  __shared__ float zs[32];
  __shared__ float w1s[3*7*64];
  __shared__ float red[256];
  if (t < 32) zs[t] = Z[b*32 + t];
  for (int i = t; i < 1344; i += 256) w1s[i] = W1[i];
  __syncthreads();
  float lsum = 0.f, lsq = 0.f;
  for (int idx = t; idx < 15232; idx += 256){
    int co = idx & 63;
    int wo = (idx >> 6) % 7;
    int ho = idx / 448;
    int kw = 6 - wo;
    float y = 0.f;
    #pragma unroll
    for (int kh = 0; kh < 3; ++kh){
      int hi = ho + kh - 2;
      if (hi >= 0 && hi < 32) y += zs[hi] * w1s[(kh*7 + kw)*64 + co];
    }
    lsum += y; lsq += y*y;
  }
  red[t] = lsum; __syncthreads();
  if (t < 64) ws[OFF_P1S + b*64 + t] = red[t] + red[t+64] + red[t+128] + red[t+192];
  __syncthreads();
  red[t] = lsq; __syncthreads();
  if (t < 64) ws[OFF_P1Q + b*64 + t] = red[t] + red[t+64] + red[t+128] + red[t+192];
}

// ============ BN finalize: partials laid out [part][nch] ============
__global__ __launch_bounds__(256) void k_fin(float* __restrict__ ws, const float* __restrict__ g,
                                             const float* __restrict__ bb, int ps, int pq, int npart,
                                             int nch, float inv_n, int ao, int co, int zlp){
  const int c = blockIdx.x, t = threadIdx.x;
  __shared__ float r1[256], r2[256];
  float s = 0.f, q = 0.f;
  for (int i = t; i < npart; i += 256){ s += ws[ps + i*nch + c]; q += ws[pq + i*nch + c]; }
  r1[t] = s; r2[t] = q; __syncthreads();
  for (int off = 128; off > 0; off >>= 1){
    if (t < off){ r1[t] += r1[t+off]; r2[t] += r2[t+off]; }
    __syncthreads();
  }
  if (t == 0){
    float m  = r1[0] * inv_n;
    float v  = r2[0] * inv_n - m*m;
    float is = rsqrtf(v + 1e-5f);
    float a  = g[c] * is;
    ws[ao + c] = a;
    ws[co + c] = bb[c] - a*m;
  }
  if (zlp && c == 0 && t == 0) ws[OFF_LP] = 0.f;
}

// ============ k1n: normalized act1 -> HBM in MFMA frag order ============
// act1n[(hi*7+wi)*64 + bg][g*8..] with g = kc*64 + j*16 + b15 (1024 shorts per pixel-bg)
__global__ __launch_bounds__(256) void k1n(const float* __restrict__ Z, const float* __restrict__ W1,
                                           const float* __restrict__ ws, unsigned short* __restrict__ a1n){
  const int bg = blockIdx.x, hi = blockIdx.y, t = threadIdx.x;
  __shared__ float zr[16][4];
  __shared__ float w1s[1344];
  __shared__ float a1s[64], c1s[64];
  if (t < 64){ a1s[t] = ws[OFF_A1+t]; c1s[t] = ws[OFF_C1+t]; }
  if (t < 64){                           // 16 batches x 4 slots (kh=3 slot stays 0)
    const int b = t >> 2, kh = t & 3;
    float v = 0.f;
    if (kh < 3){
      const int q = hi + kh - 2;
      if (q >= 0 && q < 32) v = Z[(bg*16 + b)*32 + q];
    }
    zr[b][kh] = v;
  }
  for (int i = t; i < 1344; i += 256) w1s[i] = W1[i];
  __syncthreads();
  for (int c = t; c < 896; c += 256){
    const int wi = c >> 7, g = c & 127;
    const int kc = g >> 6, j = (g >> 4) & 3, b = g & 15;
    const int ci0 = kc*32 + j*8;
    const float* wp = &w1s[(6 - wi)*64 + ci0];
    const float z0 = zr[b][0], z1 = zr[b][1], z2 = zr[b][2];
    unsigned int pk[4];
    #pragma unroll
    for (int e = 0; e < 8; e += 2){
      float y0 = z0*wp[e]       + z1*wp[448+e]   + z2*wp[896+e];
      float y1 = z0*wp[e+1]     + z1*wp[448+e+1] + z2*wp[896+e+1];
      float u0 = fmaxf(fmaf(a1s[ci0+e],   y0, c1s[ci0+e]),   0.f);
      float u1 = fmaxf(fmaf(a1s[ci0+e+1], y1, c1s[ci0+e+1]), 0.f);
      pk[e>>1] = (unsigned int)f2bu(u0) | ((unsigned int)f2bu(u1) << 16);
    }
    *(uint4*)(a1n + ((size_t)(hi*7 + wi)*64 + bg)*1024 + g*8) = *(uint4*)pk;
  }
}

// ============ deconv2 (MFMA, DMA-staged): act1n -> x2 (36,27,1024,32) ============
__global__ __launch_bounds__(256) void k2(const unsigned short* __restrict__ a1n,
                                          const unsigned short* __restrict__ fw2,
                                          unsigned short* __restrict__ x2, float* __restrict__ ws){
  const int t = threadIdx.x;
  const int bx = blockIdx.x, b0 = bx*16, ho = blockIdx.y;
  __shared__ unsigned short sa[21*1024];
  __shared__ float sred[2][4][32];
  const int w = t>>6, L = t&63;
  // pure DMA staging: 1024 shorts per pixel = TWO wave DMA issues (each covers 512 shorts)
  for (int p = w; p < 21; p += 4){
    const int r = p/7, wi = p - r*7;
    const int hi = ho - 2 + r;
    unsigned short* dst = sa + p*1024;
    if (hi >= 0 && hi < 34){
      const unsigned short* src = a1n + ((size_t)(hi*7 + wi)*64 + bx)*1024;
      gload_lds16(src + L*8,       dst);          // kc=0 half: shorts 0..511
      gload_lds16(src + 512 + L*8, dst + 512);    // kc=1 half: shorts 512..1023
    } else {
      *(uint4*)(dst + L*8) = make_uint4(0,0,0,0);
      *(uint4*)(dst + 512 + L*8) = make_uint4(0,0,0,0);
    }
  }
  __syncthreads();
  floatx4 acc[8][2];
  #pragma unroll
  for (int i = 0; i < 8; ++i){ acc[i][0] = (floatx4)0.f; acc[i][1] = (floatx4)0.f; }
  const int wiA = 2*w, wiB = (w < 3) ? 2*w + 1 : 2*w;
  for (int r = 0; r < 3; ++r){
    short8 af[3][2][2];
    #pragma unroll
    for (int kw = 0; kw < 3; ++kw)
      #pragma unroll
      for (int mt = 0; mt < 2; ++mt)
        #pragma unroll
        for (int kc = 0; kc < 2; ++kc)
          af[kw][mt][kc] = *(const short8*)(fw2 + ((((size_t)(r*3+kw)*2 + mt)*2 + kc)*64 + L)*8);
    const short8* pA = (const short8*)(sa + (size_t)(r*7 + wiA)*1024);
    const short8* pB = (const short8*)(sa + (size_t)(r*7 + wiB)*1024);
    short8 fa0 = pA[L], fa1 = pA[64+L];
    short8 fb0 = pB[L], fb1 = pB[64+L];
    #pragma unroll
    for (int idx = 0; idx < 8; ++idx){
      if (idx == 3 || idx == 7) continue;
      const int kw = (2 - idx) & 3;
      const int half = idx >> 2;
      if (half && w == 3) continue;
      short8 f0 = half ? fb0 : fa0;
      short8 f1 = half ? fb1 : fa1;
      #pragma unroll
      for (int mt = 0; mt < 2; ++mt){
        acc[idx][mt] = mfma16(af[kw][mt][0], f0, acc[idx][mt]);
        acc[idx][mt] = mfma16(af[kw][mt][1], f1, acc[idx][mt]);
      }
    }
  }
  const int bL = L & 15, jj = (L>>4)&3;
  float ss[2][4] = {{0,0,0,0},{0,0,0,0}}, sq[2][4] = {{0,0,0,0},{0,0,0,0}};
  #pragma unroll
  for (int idx = 0; idx < 8; ++idx){
    if (8*w + idx >= 27) continue;
    #pragma unroll
    for (int mt = 0; mt < 2; ++mt){
      floatx4 a = acc[idx][mt];
      ss[mt][0] += a.x; ss[mt][1] += a.y; ss[mt][2] += a.z; ss[mt][3] += a.w;
      sq[mt][0] += a.x*a.x; sq[mt][1] += a.y*a.y; sq[mt][2] += a.z*a.z; sq[mt][3] += a.w*a.w;
    }
  }
  #pragma unroll
  for (int mt = 0; mt < 2; ++mt)
    #pragma unroll
    for (int r2 = 0; r2 < 4; ++r2){
      float v1 = ss[mt][r2], v2 = sq[mt][r2];
      for (int d = 1; d < 16; d <<= 1){ v1 += __shfl_xor(v1, d, 64); v2 += __shfl_xor(v2, d, 64); }
      if (bL == 0){
        int cch = mt*16 + jj*4 + r2;
        sred[0][w][cch] = v1;
        sred[1][w][cch] = v2;
      }
    }
  __syncthreads();
  if (t < 64){
    const int cch = t & 31, j2 = t >> 5;
    float tot = sred[j2][0][cch] + sred[j2][1][cch] + sred[j2][2][cch] + sred[j2][3][cch];
    const int bid = blockIdx.y*64 + blockIdx.x;
    ws[(j2 ? OFF_P2Q : OFF_P2S) + bid*32 + cch] = tot;
  }
  unsigned short* st = sa + w*4608;
  #pragma unroll
  for (int idx = 0; idx < 8; ++idx){
    if (8*w + idx >= 27) continue;
    #pragma unroll
    for (int mt = 0; mt < 2; ++mt){
      floatx4 a = acc[idx][mt];
      uint2 pk;
      pk.x = (unsigned int)f2bu(a.x) | ((unsigned int)f2bu(a.y) << 16);
      pk.y = (unsigned int)f2bu(a.z) | ((unsigned int)f2bu(a.w) << 16);
      *(uint2*)(st + idx*576 + bL*36 + mt*16 + jj*4) = pk;
    }
  }
  const int sb = L >> 2, q2 = L & 3;
  #pragma unroll
  for (int idx = 0; idx < 8; ++idx){
    const int wo = 8*w + idx;
    if (wo >= 27) continue;
    uint4 v = *(const uint4*)(st + idx*576 + sb*36 + q2*8);
    *(uint4*)(x2 + ((size_t)(ho*27+wo)*1024 + b0 + sb)*32 + q2*8) = v;
  }
}

// ============ deconv3 (MFMA, DMA-staged, ho-pair): x2 -> x3 (36,55,1024,32) ============
__global__ __launch_bounds__(256) void k3(const unsigned short* __restrict__ x2, const unsigned short* __restrict__ fw3,
                                          unsigned short* __restrict__ x3, float* __restrict__ ws){
  const int t = threadIdx.x;
  const int b0 = blockIdx.x*16, hop = blockIdx.y, z = blockIdx.z;
  const int ho0 = hop*2;
  const int wib = (z == 0) ? 0 : ((z == 1) ? 8 : 17);
  __shared__ unsigned short sa[44*512];
  __shared__ float sa2[32], sc2[32];
  __shared__ float sred[2][4][32];
  if (t < 32){ sa2[t] = ws[OFF_A2+t]; sc2[t] = ws[OFF_C2+t]; }
  const int w = t>>6, L = t&63;
  const int bL = L & 15, jL = (L>>4)&3, ci0 = jL*8;
  for (int p = w; p < 44; p += 4){
    const int row = p/11, wl = p - row*11;
    const int hi = ho0 - 1 + row, wi = wib + wl;
    unsigned short* dst = sa + p*512;
    if (hi >= 0 && hi < 36 && wi < 27){
      const unsigned short* src = x2 + ((size_t)(hi*27 + wi)*1024 + b0 + bL)*32 + ci0;
      gload_lds16(src, dst);
    } else {
      *(uint4*)(dst + L*8) = make_uint4(0,0,0,0);
    }
  }
  __syncthreads();
  {
    float an[8], cn[8];
    #pragma unroll
    for (int e = 0; e < 8; ++e){ an[e] = sa2[ci0+e]; cn[e] = sc2[ci0+e]; }
    for (int i = t; i < 44*64; i += 256){
      const int p = i >> 6;
      const int row = p/11, wl = p - row*11;
      const int hi = ho0 - 1 + row, wi = wib + wl;
      if (hi >= 0 && hi < 36 && wi < 27){
        uint4 v = *(uint4*)(sa + (size_t)i*8);
        v.x = nrm2(v.x, an[0], cn[0], an[1], cn[1]);
        v.y = nrm2(v.y, an[2], cn[2], an[3], cn[3]);
        v.z = nrm2(v.z, an[4], cn[4], an[5], cn[5]);
        v.w = nrm2(v.w, an[6], cn[6], an[7], cn[7]);
        *(uint4*)(sa + (size_t)i*8) = v;
      }
    }
  }
  __syncthreads();
  const int s0 = z*18 + ((w==0) ? 0 : (w==1) ? 6 : (w==2) ? 10 : 14);
  const int h2 = s0 >> 1;
  const int nvalid = (w==0) ? 6 : ((z==2 && w==3) ? 5 : 4);
  floatx4 acc[2][6][2];
  #pragma unroll
  for (int hoL = 0; hoL < 2; ++hoL)
    #pragma unroll
    for (int i = 0; i < 6; ++i){ acc[hoL][i][0] = (floatx4)0.f; acc[hoL][i][1] = (floatx4)0.f; }
  for (int r = 0; r < 3; ++r){
    short8 af[3][2];
    #pragma unroll
    for (int kw = 0; kw < 3; ++kw)
      #pragma unroll
      for (int mt = 0; mt < 2; ++mt)
        af[kw][mt] = *(const short8*)(fw3 + (((size_t)(r*3+kw)*2 + mt)*64 + L)*8);
    #pragma unroll
    for (int hoL = 0; hoL < 2; ++hoL){
      const int row = hoL + r;
      short8 bb[4];
      #pragma unroll
      for (int d = 0; d < 4; ++d){
        const int wl = h2 - 1 + d - wib;
        short8 v = (short8)0;
        if (wl >= 0 && wl <= 10)
          v = *(const short8*)(sa + (size_t)(row*11 + wl)*512 + L*8);
        bb[d] = v;
      }
      #pragma unroll
      for (int idx = 0; idx < 6; ++idx){
        if (idx >= nvalid) continue;
        if ((idx & 1) == 0){
          const int d = idx >> 1;
          #pragma unroll
          for (int mt = 0; mt < 2; ++mt){
            acc[hoL][idx][mt] = mfma16(af[0][mt], bb[d],   acc[hoL][idx][mt]);
            acc[hoL][idx][mt] = mfma16(af[2][mt], bb[d+1], acc[hoL][idx][mt]);
          }
        } else {
          const int d = ((idx - 1) >> 1) + 1;
          #pragma unroll
          for (int mt = 0; mt < 2; ++mt)
            acc[hoL][idx][mt] = mfma16(af[1][mt], bb[d], acc[hoL][idx][mt]);
        }
      }
    }
  }
  const int jj = jL;
  float ss[2][4] = {{0,0,0,0},{0,0,0,0}}, sq[2][4] = {{0,0,0,0},{0,0,0,0}};
  #pragma unroll
  for (int hoL = 0; hoL < 2; ++hoL)
    #pragma unroll
    for (int idx = 0; idx < 6; ++idx){
      if (idx >= nvalid) continue;
      #pragma unroll
      for (int mt = 0; mt < 2; ++mt){
        floatx4 a = acc[hoL][idx][mt];
        ss[mt][0] += a.x; ss[mt][1] += a.y; ss[mt][2] += a.z; ss[mt][3] += a.w;
        sq[mt][0] += a.x*a.x; sq[mt][1] += a.y*a.y; sq[mt][2] += a.z*a.z; sq[mt][3] += a.w*a.w;
      }
    }
  #pragma unroll
  for (int mt = 0; mt < 2; ++mt)
    #pragma unroll
    for (int r2 = 0; r2 < 4; ++r2){
      float v1 = ss[mt][r2], v2 = sq[mt][r2];
      for (int d = 1; d < 16; d <<= 1){ v1 += __shfl_xor(v1, d, 64); v2 += __shfl_xor(v2, d, 64); }
      if (bL == 0){
        int cch = mt*16 + jj*4 + r2;
        sred[0][w][cch] = v1;
        sred[1][w][cch] = v2;
      }
    }
  __syncthreads();
  if (t < 64){
    const int cch = t & 31, j2 = t >> 5;
    float tot = sred[j2][0][cch] + sred[j2][1][cch] + sred[j2][2][cch] + sred[j2][3][cch];
    const int bid = (z*18 + hop)*64 + blockIdx.x;
    ws[(j2 ? P3Q_ABS : P3S_ABS) + bid*32 + cch] = tot;
  }
  unsigned short* st = sa + w*3456;
  const int sb = L >> 2, q2 = L & 3;
  #pragma unroll
  for (int hoL = 0; hoL < 2; ++hoL){
    #pragma unroll
    for (int idx = 0; idx < 6; ++idx){
      if (idx >= nvalid) continue;
      #pragma unroll
      for (int mt = 0; mt < 2; ++mt){
        floatx4 a = acc[hoL][idx][mt];
        uint2 pk;
        pk.x = (unsigned int)f2bu(a.x) | ((unsigned int)f2bu(a.y) << 16);
        pk.y = (unsigned int)f2bu(a.z) | ((unsigned int)f2bu(a.w) << 16);
        *(uint2*)(st + idx*576 + bL*36 + mt*16 + jj*4) = pk;
      }
    }
    #pragma unroll
    for (int idx = 0; idx < 6; ++idx){
      if (idx >= nvalid) continue;
      const int wo = s0 + idx;
      uint4 v = *(const uint4*)(st + idx*576 + sb*36 + q2*8);
      *(uint4*)(x3 + ((size_t)((ho0+hoL)*55+wo)*1024 + b0 + sb)*32 + q2*8) = v;
    }
  }
}

// ============ deconv4 (MFMA, banded A): x3 -> o4 (B,36,105) ============
__global__ __launch_bounds__(256) void k_dc4(const unsigned short* __restrict__ x3,
                                             const unsigned short* __restrict__ fw4,
                                             float* __restrict__ o4, const float* __restrict__ ws){
  const int t = threadIdx.x;
  const int w = t >> 6, L = t & 63;
  const int b0 = blockIdx.x*16;
  const int ho0 = blockIdx.y*3;
  __shared__ float a3s[32], c3s[32];
  __shared__ unsigned short fa4[30*512];
  __shared__ float rowbuf[16*113];
  if (t < 32){ a3s[t] = ws[OFF_A3+t]; c3s[t] = ws[OFF_C3+t]; }
  for (int i = t; i < 1920; i += 256)
    *(uint4*)(fa4 + (size_t)i*8) = *(const uint4*)(fw4 + (size_t)i*8);
  __syncthreads();
  const int bL = L & 15, jj = (L>>4)&3, ci0 = jj*8;
  float an[8], cn[8];
  #pragma unroll
  for (int e = 0; e < 8; ++e){ an[e] = a3s[ci0+e]; cn[e] = c3s[ci0+e]; }
  floatx4 acc[2][3];
  #pragma unroll
  for (int i = 0; i < 2; ++i)
    #pragma unroll
    for (int h = 0; h < 3; ++h) acc[i][h] = (floatx4)0.f;
  for (int e = 0; e < 5; ++e){
    const int hi = ho0 - 1 + e;
    if (hi < 0 || hi >= 36) continue;
    #pragma unroll
    for (int ts = 0; ts < 2; ++ts){
      const int T = w + ts*4;
      if (T >= 7) continue;
      #pragma unroll 5
      for (int d = 0; d < 10; ++d){
        const int wi = 8*T + d;
        short8 bf;
        if (wi < 55){
          uint4 v = *(const uint4*)(x3 + ((size_t)(hi*55 + wi)*1024 + b0 + bL)*32 + ci0);
          v.x = nrm2(v.x, an[0], cn[0], an[1], cn[1]);
          v.y = nrm2(v.y, an[2], cn[2], an[3], cn[3]);
          v.z = nrm2(v.z, an[4], cn[4], an[5], cn[5]);
          v.w = nrm2(v.w, an[6], cn[6], an[7], cn[7]);
          bf = __builtin_bit_cast(short8, v);
        } else {
          bf = (short8)0;
        }
        #pragma unroll
        for (int hl = 0; hl < 3; ++hl){
          const int r = e - hl;
          if (r < 0 || r > 2) continue;
          short8 af = *(const short8*)(fa4 + ((size_t)(r*10 + d)*64 + L)*8);
          acc[ts][hl] = mfma16(af, bf, acc[ts][hl]);
        }
      }
    }
  }
  #pragma unroll
  for (int hl = 0; hl < 3; ++hl){
    __syncthreads();
    #pragma unroll
    for (int ts = 0; ts < 2; ++ts){
      const int T = w + ts*4;
      if (T >= 7) continue;
      floatx4 a = acc[ts][hl];
      float vals[4] = {a.x, a.y, a.z, a.w};
      #pragma unroll
      for (int reg = 0; reg < 4; ++reg){
        const int wo = 16*T + jj*4 + reg;
        if (wo < 105) rowbuf[bL*113 + wo] = vals[reg];
      }
    }
    __syncthreads();
    const int ho = ho0 + hl;
    for (int i = t; i < 1680; i += 256){
      const int bb = i / 105, wo = i - bb*105;
      o4[(size_t)(b0 + bb)*3780 + ho*105 + wo] = rowbuf[bb*113 + wo];
    }
  }
}

// ============ node softmax / outputs ============
__global__ __launch_bounds__(256) void k_node(const float* __restrict__ o4, float* __restrict__ dout,
                                              float* __restrict__ ws){
  const int t = threadIdx.x;
  const int tg = blockIdx.x*256 + t;
  __shared__ float red[256];
  float lp = 0.f;
  {
    int b = tg / 30, n = tg - b*30;
    const float* p = o4 + (size_t)b*3780 + n*126;
    float l[6]; float mx = -1e30f;
    #pragma unroll
    for (int j = 0; j < 6; ++j){ l[j] = p[j]; mx = fmaxf(mx, l[j]); }
    float e[6]; float s = 0.f;
    #pragma unroll
    for (int j = 0; j < 6; ++j){ e[j] = expf(l[j] - mx); s += e[j]; }
    float inv = 1.f / s;
    int am = 0; float best = e[0];
    #pragma unroll
    for (int j = 1; j < 6; ++j){ if (e[j] > best){ best = e[j]; am = j; } }
    #pragma unroll
    for (int j = 0; j < 5; ++j) dout[OUT0 + (size_t)tg*5 + j] = e[j+1]*inv;
    dout[OUT3 + tg] = 1.f - e[0]*inv;
    #pragma unroll
    for (int j = 0; j < 5; ++j) dout[OUT6 + (size_t)tg*5 + j] = (am == j+1) ? 1.f : 0.f;
    dout[OUT8 + tg] = (am != 0) ? 1.f : 0.f;
    dout[OUT5 + tg] = (float)b;
    lp = logf(best*inv + 1e-7f);
  }
  red[t] = lp; __syncthreads();
  for (int off = 128; off > 0; off >>= 1){ if (t < off) red[t] += red[t+off]; __syncthreads(); }
  if (t == 0) atomicAdd(&ws[OFF_LP], red[0]);
}

// ============ edge softmax / outputs ============
__global__ __launch_bounds__(256) void k_edge(const float* __restrict__ o4, float* __restrict__ dout,
                                              float* __restrict__ ws){
  const int t = threadIdx.x;
  const int tg = blockIdx.x*256 + t;
  __shared__ float red[256];
  float lp = 0.f;
  {
    int b = tg / 435, k = tg - b*435;
    int i = (int)((59.0f - sqrtf((float)(3481 - 8*k))) * 0.5f);
    int rem = k - ((i*(59 - i)) >> 1);
    if (rem < 0){ i -= 1; rem = k - ((i*(59 - i)) >> 1); }
    else if (rem >= 29 - i){ rem -= 29 - i; i += 1; }
    int j = i + 1 + rem;
    const float* p = o4 + (size_t)b*3780 + i*126 + 6 + j*4;
    float l0 = p[0], l1 = p[1], l2 = p[2], l3 = p[3];
    float mx = fmaxf(fmaxf(l0, l1), fmaxf(l2, l3));
    float e0 = expf(l0-mx), e1 = expf(l1-mx), e2 = expf(l2-mx), e3 = expf(l3-mx);
    float inv = 1.f / (e0 + e1 + e2 + e3);
    float pr0 = e0*inv, pr1 = e1*inv, pr2 = e2*inv, pr3 = e3*inv;
    int am = 0; float best = pr0;
    if (pr1 > best){ best = pr1; am = 1; }
    if (pr2 > best){ best = pr2; am = 2; }
    if (pr3 > best){ best = pr3; am = 3; }
    size_t e1i = (size_t)b*870 + k, e2i = e1i + 435;
    dout[OUT2 + e1i*3 + 0] = pr1; dout[OUT2 + e1i*3 + 1] = pr2; dout[OUT2 + e1i*3 + 2] = pr3;
    dout[OUT2 + e2i*3 + 0] = pr1; dout[OUT2 + e2i*3 + 1] = pr2; dout[OUT2 + e2i*3 + 2] = pr3;
    dout[OUT4 + e1i] = 1.f - pr0;  dout[OUT4 + e2i] = 1.f - pr0;
    float h1 = (am == 1) ? 1.f : 0.f, h2 = (am == 2) ? 1.f : 0.f, h3 = (am == 3) ? 1.f : 0.f;
    dout[OUT7 + e1i*3 + 0] = h1; dout[OUT7 + e1i*3 + 1] = h2; dout[OUT7 + e1i*3 + 2] = h3;
    dout[OUT7 + e2i*3 + 0] = h1; dout[OUT7 + e2i*3 + 1] = h2; dout[OUT7 + e2i*3 + 2] = h3;
    dout[OUT9 + e1i] = (am != 0) ? 1.f : 0.f;  dout[OUT9 + e2i] = (am != 0) ? 1.f : 0.f;
    if (b == 0){
      dout[OUT1 + k]        = (float)i;
      dout[OUT1 + 435 + k]  = (float)j;
      dout[OUT1 + 870 + k]  = (float)j;
      dout[OUT1 + 1305 + k] = (float)i;
    }
    lp = logf(best + 1e-7f);
  }
  red[t] = lp; __syncthreads();
  for (int off = 128; off > 0; off >>= 1){ if (t < off) red[t] += red[t+off]; __syncthreads(); }
  if (t == 0) atomicAdd(&ws[OFF_LP], red[0]);
}

__global__ void k_lp_copy(float* __restrict__ dout, const float* __restrict__ ws){
  if (threadIdx.x == 0 && blockIdx.x == 0) dout[OUT10] = ws[OFF_LP];
}

extern "C" void kernel_launch(void* const* d_in, const int* in_sizes, int n_in,
                              void* d_out, int out_size, void* d_ws, size_t ws_size,
                              hipStream_t stream) {
  const float* Z  = (const float*)d_in[0];
  const float* W1 = (const float*)d_in[1];
  const float* W2 = (const float*)d_in[2];
  const float* W3 = (const float*)d_in[3];
  const float* W4 = (const float*)d_in[4];
  const float* g1 = (const float*)d_in[5];
  const float* b1 = (const float*)d_in[6];
  const float* g2 = (const float*)d_in[7];
  const float* b2 = (const float*)d_in[8];
  const float* g3 = (const float*)d_in[9];
  const float* b3 = (const float*)d_in[10];

  float* ws  = (float*)d_ws;
  char*  wsb = (char*)d_ws;
  unsigned short* fw2 = (unsigned short*)(wsb + FW2_BYTE);
  unsigned short* fw3 = (unsigned short*)(wsb + FW3_BYTE);
  unsigned short* fw4 = (unsigned short*)(wsb + FW4_BYTE);
  unsigned short* a1n = (unsigned short*)(wsb + A1N_BYTE);
  unsigned short* x2u = (unsigned short*)(wsb + X2_BYTE);
  unsigned short* x3u = (unsigned short*)(wsb + X3_BYTE);
  float*          o4  = (float*)(wsb + O4_BYTE);
  float* dout = (float*)d_out;
  (void)in_sizes; (void)n_in; (void)out_size; (void)ws_size;

  k_prep<<<dim3(9), dim3(256), 0, stream>>>(W2, W3, W4, fw2, fw3, fw4);
  k_dc1<<<dim3(1024), dim3(256), 0, stream>>>(Z, W1, ws);
  k_fin<<<dim3(64), dim3(256), 0, stream>>>(ws, g1, b1, OFF_P1S, OFF_P1Q, 1024, 64,
                                            1.f/243712.f, OFF_A1, OFF_C1, 0);
  k1n<<<dim3(64, 34), dim3(256), 0, stream>>>(Z, W1, ws, a1n);
  k2<<<dim3(64, 36), dim3(256), 0, stream>>>(a1n, fw2, x2u, ws);
  k_fin<<<dim3(32), dim3(256), 0, stream>>>(ws, g2, b2, OFF_P2S, OFF_P2Q, 2304, 32,
                                            1.f/995328.f, OFF_A2, OFF_C2, 0);
  k3<<<dim3(64, 18, 3), dim3(256), 0, stream>>>(x2u, fw3, x3u, ws);
  k_fin<<<dim3(32), dim3(256), 0, stream>>>(ws, g3, b3, P3S_ABS, P3Q_ABS, 3456, 32,
                                            1.f/2027520.f, OFF_A3, OFF_C3, 1);
  k_dc4<<<dim3(64, 12), dim3(256), 0, stream>>>(x3u, fw4, o4, ws);
  k_node<<<dim3(120), dim3(256), 0, stream>>>(o4, dout, ws);
  k_edge<<<dim3(1740), dim3(256), 0, stream>>>(o4, dout, ws);
  k_lp_copy<<<dim3(1), dim3(64), 0, stream>>>(dout, ws);
}